// Round 1
// baseline (1076.765 us; speedup 1.0000x reference)
//
#include <hip/hip_runtime.h>
#include <math.h>

#define LN_EPS 1e-5f

__device__ __forceinline__ float gelu_f(float v) {
    return 0.5f * v * (1.0f + erff(v * 0.70710678118654752f));
}

// ---------------------------------------------------------------------------
// Position-MLP engine: 256 threads = 64 positions (p = tid&63) x 4 j-groups
// (jg = tid>>6, wave-uniform).  Features live in LDS rows of stride 65
// (banks (p+c)%32 -> conflict-free).  Weights are read at wave-uniform
// addresses so they can become scalar loads.
// ---------------------------------------------------------------------------
template<int KIN>
__device__ __forceinline__ void layer_ln_gelu(
    const float* __restrict__ W, const float* __restrict__ bias,
    const float* __restrict__ g, const float* __restrict__ be,
    const float* __restrict__ bufIn, float* __restrict__ bufOut,
    float* __restrict__ red, int p, int jg)
{
    float acc[16];
    #pragma unroll
    for (int q = 0; q < 4; ++q) {
        float4 b4 = ((const float4*)bias)[jg*4 + q];
        acc[4*q+0] = b4.x; acc[4*q+1] = b4.y; acc[4*q+2] = b4.z; acc[4*q+3] = b4.w;
    }
    for (int c = 0; c < KIN; ++c) {
        float xv = bufIn[p*65 + c];
        const float4* wrow = (const float4*)(W + c*64) + jg*4;
        #pragma unroll
        for (int q = 0; q < 4; ++q) {
            float4 w4 = wrow[q];
            acc[4*q+0] = fmaf(xv, w4.x, acc[4*q+0]);
            acc[4*q+1] = fmaf(xv, w4.y, acc[4*q+1]);
            acc[4*q+2] = fmaf(xv, w4.z, acc[4*q+2]);
            acc[4*q+3] = fmaf(xv, w4.w, acc[4*q+3]);
        }
    }
    float s1 = 0.f, s2 = 0.f;
    #pragma unroll
    for (int k = 0; k < 16; ++k) { s1 += acc[k]; s2 = fmaf(acc[k], acc[k], s2); }
    red[jg*64 + p]       = s1;
    red[256 + jg*64 + p] = s2;
    __syncthreads();
    float mu = (red[p] + red[64+p] + red[128+p] + red[192+p]) * 0.015625f;
    float ms = (red[256+p] + red[320+p] + red[384+p] + red[448+p]) * 0.015625f;
    float rstd = rsqrtf(ms - mu*mu + LN_EPS);
    #pragma unroll
    for (int k = 0; k < 16; ++k) {
        int o = jg*16 + k;
        float v = (acc[k] - mu) * rstd * g[o] + be[o];
        bufOut[p*65 + o] = gelu_f(v);
    }
    __syncthreads();
}

__device__ __forceinline__ void layer_final96(
    const float* __restrict__ W, const float* __restrict__ bias,
    const float* __restrict__ bufIn, int p, int jg, float out[24])
{
    #pragma unroll
    for (int q = 0; q < 6; ++q) {
        float4 b4 = ((const float4*)bias)[jg*6 + q];
        out[4*q+0] = b4.x; out[4*q+1] = b4.y; out[4*q+2] = b4.z; out[4*q+3] = b4.w;
    }
    for (int c = 0; c < 64; ++c) {
        float xv = bufIn[p*65 + c];
        const float4* wrow = (const float4*)(W + c*96) + jg*6;
        #pragma unroll
        for (int q = 0; q < 6; ++q) {
            float4 w4 = wrow[q];
            out[4*q+0] = fmaf(xv, w4.x, out[4*q+0]);
            out[4*q+1] = fmaf(xv, w4.y, out[4*q+1]);
            out[4*q+2] = fmaf(xv, w4.z, out[4*q+2]);
            out[4*q+3] = fmaf(xv, w4.w, out[4*q+3]);
        }
    }
}

// K1: W-basis MLP.  grid 4608 = (b*192+h)*3 + wq; block 256.
__global__ __launch_bounds__(256) void k_mlp_w(
    const float* __restrict__ x,
    const float* __restrict__ W0, const float* __restrict__ b0,
    const float* __restrict__ g0, const float* __restrict__ be0,
    const float* __restrict__ W1, const float* __restrict__ b1,
    const float* __restrict__ g1, const float* __restrict__ be1,
    const float* __restrict__ W2, const float* __restrict__ b2,
    float* __restrict__ wb_r, float* __restrict__ wb_i)
{
    __shared__ float bufA[64*65];
    __shared__ float bufB[64*65];
    __shared__ float red[512];
    int tid = threadIdx.x;
    int p  = tid & 63;
    int jg = __builtin_amdgcn_readfirstlane(tid >> 6);
    int wq = blockIdx.x % 3;
    int bh = blockIdx.x / 3;              // b*192 + h
    int b  = bh / 192, h = bh % 192;
    int w0 = wq * 64;
    for (int c = jg; c < 64; c += 4)
        bufA[p*65 + c] = x[((b*64 + c)*192 + h)*192 + (w0 + p)];
    if (jg == 0)
        bufA[p*65 + 64] = (float)(w0 + p) * (1.0f/191.0f);
    __syncthreads();
    layer_ln_gelu<65>(W0, b0, g0, be0, bufA, bufB, red, p, jg);
    layer_ln_gelu<64>(W1, b1, g1, be1, bufB, bufA, red, p, jg);
    float o24[24];
    layer_final96(W2, b2, bufA, p, jg, o24);
    int pix = bh*192 + (w0 + p);
    float* dst = (jg < 2) ? (wb_r + pix*48 + jg*24)
                          : (wb_i + pix*48 + (jg-2)*24);
    #pragma unroll
    for (int q = 0; q < 6; ++q)
        ((float4*)dst)[q] = make_float4(o24[4*q], o24[4*q+1], o24[4*q+2], o24[4*q+3]);
}

// K3: H-basis MLP.  grid 1152 = (b*48+m)*3 + hq; block 256.
__global__ __launch_bounds__(256) void k_mlp_h(
    const float* __restrict__ t_r,
    const float* __restrict__ W0, const float* __restrict__ b0,
    const float* __restrict__ g0, const float* __restrict__ be0,
    const float* __restrict__ W1, const float* __restrict__ b1,
    const float* __restrict__ g1, const float* __restrict__ be1,
    const float* __restrict__ W2, const float* __restrict__ b2,
    float* __restrict__ hb_r, float* __restrict__ hb_i)
{
    __shared__ float bufA[64*65];
    __shared__ float bufB[64*65];
    __shared__ float red[512];
    int tid = threadIdx.x;
    int p  = tid & 63;
    int jg = __builtin_amdgcn_readfirstlane(tid >> 6);
    int hq = blockIdx.x % 3;
    int bm = blockIdx.x / 3;              // b*48 + m
    int h0 = hq * 64;
    for (int c = jg; c < 64; c += 4)
        bufA[p*65 + c] = t_r[(bm*64 + c)*192 + (h0 + p)];
    if (jg == 0)
        bufA[p*65 + 64] = (float)(h0 + p) * (1.0f/191.0f);
    __syncthreads();
    layer_ln_gelu<65>(W0, b0, g0, be0, bufA, bufB, red, p, jg);
    layer_ln_gelu<64>(W1, b1, g1, be1, bufB, bufA, red, p, jg);
    float o24[24];
    layer_final96(W2, b2, bufA, p, jg, o24);
    int pix = bm*192 + (h0 + p);
    float* dst = (jg < 2) ? (hb_r + pix*48 + jg*24)
                          : (hb_i + pix*48 + (jg-2)*24);
    #pragma unroll
    for (int q = 0; q < 6; ++q)
        ((float4*)dst)[q] = make_float4(o24[4*q], o24[4*q+1], o24[4*q+2], o24[4*q+3]);
}

// K2: t[b,c,h,m] = sum_w x[b,c,h,w]*wb[b,h,w,m].  grid 1536 = b*192+h.
// t stored (B,M2,C,H) for coalesced downstream reads.
__global__ __launch_bounds__(256) void k2_t(
    const float* __restrict__ x,
    const float* __restrict__ wb_r, const float* __restrict__ wb_i,
    float* __restrict__ t_r, float* __restrict__ t_i)
{
    __shared__ float xs[64*33];
    __shared__ float wbs[32*96];
    int bh = blockIdx.x;                  // b*192 + h
    int b = bh / 192, h = bh % 192;
    int tid = threadIdx.x;
    int c = tid >> 2, mg = tid & 3;
    float accr[12], acci[12];
    #pragma unroll
    for (int k = 0; k < 12; ++k) { accr[k] = 0.f; acci[k] = 0.f; }
    for (int w0 = 0; w0 < 192; w0 += 32) {
        for (int idx = tid; idx < 2048; idx += 256) {
            int cc = idx >> 5, ww = idx & 31;
            xs[cc*33 + ww] = x[((b*64 + cc)*192 + h)*192 + (w0 + ww)];
        }
        for (int idx = tid; idx < 1536; idx += 256) {
            int ww = idx / 48, mm = idx % 48;
            int g = (bh*192 + (w0 + ww))*48 + mm;
            wbs[ww*96 + mm]      = wb_r[g];
            wbs[ww*96 + 48 + mm] = wb_i[g];
        }
        __syncthreads();
        for (int ww = 0; ww < 32; ++ww) {
            float xv = xs[c*33 + ww];
            const float4* wr4 = (const float4*)(wbs + ww*96 + mg*12);
            const float4* wi4 = (const float4*)(wbs + ww*96 + 48 + mg*12);
            #pragma unroll
            for (int q = 0; q < 3; ++q) {
                float4 wr = wr4[q], wi = wi4[q];
                accr[4*q+0] = fmaf(xv, wr.x, accr[4*q+0]);
                accr[4*q+1] = fmaf(xv, wr.y, accr[4*q+1]);
                accr[4*q+2] = fmaf(xv, wr.z, accr[4*q+2]);
                accr[4*q+3] = fmaf(xv, wr.w, accr[4*q+3]);
                acci[4*q+0] = fmaf(xv, wi.x, acci[4*q+0]);
                acci[4*q+1] = fmaf(xv, wi.y, acci[4*q+1]);
                acci[4*q+2] = fmaf(xv, wi.z, acci[4*q+2]);
                acci[4*q+3] = fmaf(xv, wi.w, acci[4*q+3]);
            }
        }
        __syncthreads();
    }
    #pragma unroll
    for (int k = 0; k < 12; ++k) {
        int m = mg*12 + k;
        int a = ((b*48 + m)*64 + c)*192 + h;
        t_r[a] = accr[k];
        t_i[a] = acci[k];
    }
}

// K4: t2[b,c,n,m] = sum_h t[b,c,h,m]*hb[b,m,h,n].  grid 384 = b*48+m.
__global__ __launch_bounds__(256) void k4_t2(
    const float* __restrict__ t_r, const float* __restrict__ t_i,
    const float* __restrict__ hb_r, const float* __restrict__ hb_i,
    float* __restrict__ t2_r, float* __restrict__ t2_i)
{
    __shared__ float tsr[64*33], tsi[64*33];
    __shared__ float hbs[32*96];
    int bm = blockIdx.x;                  // b*48 + m
    int b = bm / 48, m = bm % 48;
    int tid = threadIdx.x;
    int c = tid >> 2, ng = tid & 3;
    float ar[12], ai[12];
    #pragma unroll
    for (int k = 0; k < 12; ++k) { ar[k] = 0.f; ai[k] = 0.f; }
    for (int h0 = 0; h0 < 192; h0 += 32) {
        for (int idx = tid; idx < 2048; idx += 256) {
            int cc = idx >> 5, hh = idx & 31;
            int g = (bm*64 + cc)*192 + (h0 + hh);
            tsr[cc*33 + hh] = t_r[g];
            tsi[cc*33 + hh] = t_i[g];
        }
        for (int idx = tid; idx < 1536; idx += 256) {
            int hh = idx / 48, nn = idx % 48;
            int g = (bm*192 + (h0 + hh))*48 + nn;
            hbs[hh*96 + nn]      = hb_r[g];
            hbs[hh*96 + 48 + nn] = hb_i[g];
        }
        __syncthreads();
        for (int hh = 0; hh < 32; ++hh) {
            float tr = tsr[c*33 + hh];
            float ti = tsi[c*33 + hh];
            const float4* hr4 = (const float4*)(hbs + hh*96 + ng*12);
            const float4* hi4 = (const float4*)(hbs + hh*96 + 48 + ng*12);
            #pragma unroll
            for (int q = 0; q < 3; ++q) {
                float4 hr = hr4[q], hi = hi4[q];
                ar[4*q+0] = fmaf(tr, hr.x, fmaf(-ti, hi.x, ar[4*q+0]));
                ai[4*q+0] = fmaf(tr, hi.x, fmaf( ti, hr.x, ai[4*q+0]));
                ar[4*q+1] = fmaf(tr, hr.y, fmaf(-ti, hi.y, ar[4*q+1]));
                ai[4*q+1] = fmaf(tr, hi.y, fmaf( ti, hr.y, ai[4*q+1]));
                ar[4*q+2] = fmaf(tr, hr.z, fmaf(-ti, hi.z, ar[4*q+2]));
                ai[4*q+2] = fmaf(tr, hi.z, fmaf( ti, hr.z, ai[4*q+2]));
                ar[4*q+3] = fmaf(tr, hr.w, fmaf(-ti, hi.w, ar[4*q+3]));
                ai[4*q+3] = fmaf(tr, hi.w, fmaf( ti, hr.w, ai[4*q+3]));
            }
        }
        __syncthreads();
    }
    #pragma unroll
    for (int k = 0; k < 12; ++k) {
        int n = ng*12 + k;
        int a = (b*64 + c)*2304 + n*48 + m;
        t2_r[a] = ar[k];
        t2_i[a] = ai[k];
    }
}

// K5: proc[b,o,nm] = sum_i t2[b,i,nm]*Wf[o,i,nm].  grid 288 = 32 og x 9 chunks.
__global__ __launch_bounds__(256) void k5_proc(
    const float* __restrict__ t2_r, const float* __restrict__ t2_i,
    const float* __restrict__ fr, const float* __restrict__ fi,
    float* __restrict__ proc_r, float* __restrict__ proc_i)
{
    int og = blockIdx.x & 31;
    int ch = blockIdx.x >> 5;
    int nm = ch*256 + threadIdx.x;
    int o0 = og*2;
    float p0r[8], p0i[8], p1r[8], p1i[8];
    #pragma unroll
    for (int bb = 0; bb < 8; ++bb) { p0r[bb]=0.f; p0i[bb]=0.f; p1r[bb]=0.f; p1i[bb]=0.f; }
    for (int i = 0; i < 64; ++i) {
        float w0r = fr[(o0*64 + i)*2304 + nm];
        float w0i = fi[(o0*64 + i)*2304 + nm];
        float w1r = fr[((o0+1)*64 + i)*2304 + nm];
        float w1i = fi[((o0+1)*64 + i)*2304 + nm];
        #pragma unroll
        for (int bb = 0; bb < 8; ++bb) {
            float tr = t2_r[(bb*64 + i)*2304 + nm];
            float ti = t2_i[(bb*64 + i)*2304 + nm];
            p0r[bb] = fmaf(tr, w0r, fmaf(-ti, w0i, p0r[bb]));
            p0i[bb] = fmaf(tr, w0i, fmaf( ti, w0r, p0i[bb]));
            p1r[bb] = fmaf(tr, w1r, fmaf(-ti, w1i, p1r[bb]));
            p1i[bb] = fmaf(tr, w1i, fmaf( ti, w1r, p1i[bb]));
        }
    }
    #pragma unroll
    for (int bb = 0; bb < 8; ++bb) {
        proc_r[(bb*64 + o0)*2304 + nm]     = p0r[bb];
        proc_i[(bb*64 + o0)*2304 + nm]     = p0i[bb];
        proc_r[(bb*64 + o0 + 1)*2304 + nm] = p1r[bb];
        proc_i[(bb*64 + o0 + 1)*2304 + nm] = p1i[bb];
    }
}

// K6: rec_h[b,o,h,m] = sum_n proc[b,o,n,m]*conj(hb)[b,m,h,n].
// grid 1536 = (b*48+m)*4 + hq.  rec_h stored (B,M2,H,O).
__global__ __launch_bounds__(256) void k6_rech(
    const float* __restrict__ proc_r, const float* __restrict__ proc_i,
    const float* __restrict__ hb_r, const float* __restrict__ hb_i,
    float* __restrict__ rh_r, float* __restrict__ rh_i)
{
    __shared__ float psr[64*49], psi[64*49];
    __shared__ float hsr[48*52], hsi[48*52];
    int hq = blockIdx.x & 3;
    int bm = blockIdx.x >> 2;             // b*48 + m
    int b = bm / 48, m = bm % 48;
    int tid = threadIdx.x;
    int o = tid & 63, hg = tid >> 6;
    for (int idx = tid; idx < 3072; idx += 256) {
        int oo = idx / 48, nn = idx % 48;
        int g = (b*64 + oo)*2304 + nn*48 + m;
        psr[oo*49 + nn] = proc_r[g];
        psi[oo*49 + nn] = proc_i[g];
    }
    for (int idx = tid; idx < 2304; idx += 256) {
        int hh = idx / 48, nn = idx % 48;
        int g = (bm*192 + hq*48 + hh)*48 + nn;
        hsr[hh*52 + nn] = hb_r[g];
        hsi[hh*52 + nn] = hb_i[g];
    }
    __syncthreads();
    float accr[12], acci[12];
    #pragma unroll
    for (int j = 0; j < 12; ++j) { accr[j]=0.f; acci[j]=0.f; }
    for (int n4 = 0; n4 < 48; n4 += 4) {
        float prv[4], piv[4];
        #pragma unroll
        for (int q = 0; q < 4; ++q) {
            prv[q] = psr[o*49 + n4 + q];
            piv[q] = psi[o*49 + n4 + q];
        }
        #pragma unroll
        for (int j = 0; j < 12; ++j) {
            const float4 hr = *(const float4*)(hsr + (hg*12 + j)*52 + n4);
            const float4 hi = *(const float4*)(hsi + (hg*12 + j)*52 + n4);
            accr[j] += prv[0]*hr.x + piv[0]*hi.x
                     + prv[1]*hr.y + piv[1]*hi.y
                     + prv[2]*hr.z + piv[2]*hi.z
                     + prv[3]*hr.w + piv[3]*hi.w;
            acci[j] += piv[0]*hr.x - prv[0]*hi.x
                     + piv[1]*hr.y - prv[1]*hi.y
                     + piv[2]*hr.z - prv[2]*hi.z
                     + piv[3]*hr.w - prv[3]*hi.w;
        }
    }
    #pragma unroll
    for (int j = 0; j < 12; ++j) {
        int h = hq*48 + hg*12 + j;
        int a = (bm*192 + h)*64 + o;
        rh_r[a] = accr[j];
        rh_i[a] = acci[j];
    }
}

// K7: y[b,o,h,w] = (1/(H*W)) * sum_m rec_h[b,o,h,m]*conj(wb)[b,h,w,m] (real part).
// grid 4608 = (b*192+h)*3 + wq.
__global__ __launch_bounds__(256) void k7_rec(
    const float* __restrict__ rh_r, const float* __restrict__ rh_i,
    const float* __restrict__ wb_r, const float* __restrict__ wb_i,
    float* __restrict__ y)
{
    __shared__ float asr[48*64], asi[48*64];
    __shared__ float wsr[64*49], wsi[64*49];
    int wq = blockIdx.x % 3;
    int bh = blockIdx.x / 3;              // b*192 + h
    int b = bh / 192, h = bh % 192;
    int tid = threadIdx.x;
    int w_l = tid & 63, og = tid >> 6;
    for (int idx = tid; idx < 3072; idx += 256) {
        int mm = idx >> 6, oo = idx & 63;
        int g = ((b*48 + mm)*192 + h)*64 + oo;
        asr[idx] = rh_r[g];
        asi[idx] = rh_i[g];
    }
    for (int idx = tid; idx < 3072; idx += 256) {
        int ww = idx / 48, mm = idx % 48;
        int g = (bh*192 + wq*64 + ww)*48 + mm;
        wsr[ww*49 + mm] = wb_r[g];
        wsi[ww*49 + mm] = wb_i[g];
    }
    __syncthreads();
    float acc[16];
    #pragma unroll
    for (int k = 0; k < 16; ++k) acc[k] = 0.f;
    for (int m = 0; m < 48; ++m) {
        float wr = wsr[w_l*49 + m];
        float wi = wsi[w_l*49 + m];
        #pragma unroll
        for (int q = 0; q < 4; ++q) {
            const float4 arv = *(const float4*)(asr + m*64 + og*16 + q*4);
            const float4 aiv = *(const float4*)(asi + m*64 + og*16 + q*4);
            acc[4*q+0] = fmaf(arv.x, wr, fmaf(aiv.x, wi, acc[4*q+0]));
            acc[4*q+1] = fmaf(arv.y, wr, fmaf(aiv.y, wi, acc[4*q+1]));
            acc[4*q+2] = fmaf(arv.z, wr, fmaf(aiv.z, wi, acc[4*q+2]));
            acc[4*q+3] = fmaf(arv.w, wr, fmaf(aiv.w, wi, acc[4*q+3]));
        }
    }
    const float s = 1.0f / 36864.0f;
    #pragma unroll
    for (int k = 0; k < 16; ++k) {
        int o = og*16 + k;
        y[((b*64 + o)*192 + h)*192 + wq*64 + w_l] = acc[k] * s;
    }
}

// K8: mixer GEMM + channel-LN + GELU + shortcut GEMM + GELU.  grid 4608.
__global__ __launch_bounds__(256) void k8_final(
    const float* __restrict__ y, const float* __restrict__ x,
    const float* __restrict__ mw, const float* __restrict__ mb,
    const float* __restrict__ nrm_g, const float* __restrict__ nrm_b,
    const float* __restrict__ sw, const float* __restrict__ sb,
    float* __restrict__ out)
{
    __shared__ float ys[64*65], xs[64*65];
    __shared__ float mws[64*68], sws[64*68];
    __shared__ float red[512];
    int wq = blockIdx.x % 3;
    int bh = blockIdx.x / 3;
    int b = bh / 192, h = bh % 192;
    int tid = threadIdx.x;
    int w_l = tid & 63, og = tid >> 6;
    int w0 = wq * 64;
    for (int cc = og; cc < 64; cc += 4) {
        int g = ((b*64 + cc)*192 + h)*192 + w0 + w_l;
        ys[cc*65 + w_l] = y[g];
        xs[cc*65 + w_l] = x[g];
    }
    for (int idx = tid; idx < 4096; idx += 256) {
        int oo = idx >> 6, cc = idx & 63;
        mws[cc*68 + oo] = mw[idx];
        sws[cc*68 + oo] = sw[idx];
    }
    __syncthreads();
    float accy[16], accs[16];
    #pragma unroll
    for (int k = 0; k < 16; ++k) { accy[k]=0.f; accs[k]=0.f; }
    for (int cc = 0; cc < 64; ++cc) {
        float yv = ys[cc*65 + w_l];
        float xv = xs[cc*65 + w_l];
        #pragma unroll
        for (int q = 0; q < 4; ++q) {
            const float4 m4 = *(const float4*)(mws + cc*68 + og*16 + q*4);
            const float4 s4 = *(const float4*)(sws + cc*68 + og*16 + q*4);
            accy[4*q+0] = fmaf(yv, m4.x, accy[4*q+0]);
            accy[4*q+1] = fmaf(yv, m4.y, accy[4*q+1]);
            accy[4*q+2] = fmaf(yv, m4.z, accy[4*q+2]);
            accy[4*q+3] = fmaf(yv, m4.w, accy[4*q+3]);
            accs[4*q+0] = fmaf(xv, s4.x, accs[4*q+0]);
            accs[4*q+1] = fmaf(xv, s4.y, accs[4*q+1]);
            accs[4*q+2] = fmaf(xv, s4.z, accs[4*q+2]);
            accs[4*q+3] = fmaf(xv, s4.w, accs[4*q+3]);
        }
    }
    float s1 = 0.f, s2 = 0.f;
    #pragma unroll
    for (int k = 0; k < 16; ++k) {
        int o = og*16 + k;
        accy[k] += mb[o];
        s1 += accy[k];
        s2 = fmaf(accy[k], accy[k], s2);
    }
    red[og*64 + w_l]       = s1;
    red[256 + og*64 + w_l] = s2;
    __syncthreads();
    float mu = (red[w_l] + red[64+w_l] + red[128+w_l] + red[192+w_l]) * 0.015625f;
    float ms = (red[256+w_l] + red[320+w_l] + red[384+w_l] + red[448+w_l]) * 0.015625f;
    float rstd = rsqrtf(ms - mu*mu + LN_EPS);
    #pragma unroll
    for (int k = 0; k < 16; ++k) {
        int o = og*16 + k;
        float v = (accy[k] - mu) * rstd * nrm_g[o] + nrm_b[o];
        v = gelu_f(v);
        float sc = accs[k] + sb[o];
        out[((b*64 + o)*192 + h)*192 + w0 + w_l] = gelu_f(v + sc);
    }
}

extern "C" void kernel_launch(void* const* d_in, const int* in_sizes, int n_in,
                              void* d_out, int out_size, void* d_ws, size_t ws_size,
                              hipStream_t stream)
{
    (void)in_sizes; (void)n_in; (void)out_size; (void)ws_size;
    const float* x    = (const float*)d_in[0];
    const float* wW0  = (const float*)d_in[1];
    const float* wb0  = (const float*)d_in[2];
    const float* wg0  = (const float*)d_in[3];
    const float* wbe0 = (const float*)d_in[4];
    const float* wW1  = (const float*)d_in[5];
    const float* wb1  = (const float*)d_in[6];
    const float* wg1  = (const float*)d_in[7];
    const float* wbe1 = (const float*)d_in[8];
    const float* wW2  = (const float*)d_in[9];
    const float* wb2  = (const float*)d_in[10];
    const float* hW0  = (const float*)d_in[11];
    const float* hb0  = (const float*)d_in[12];
    const float* hg0  = (const float*)d_in[13];
    const float* hbe0 = (const float*)d_in[14];
    const float* hW1  = (const float*)d_in[15];
    const float* hb1  = (const float*)d_in[16];
    const float* hg1  = (const float*)d_in[17];
    const float* hbe1 = (const float*)d_in[18];
    const float* hW2  = (const float*)d_in[19];
    const float* hb2  = (const float*)d_in[20];
    const float* fr   = (const float*)d_in[21];
    const float* fi   = (const float*)d_in[22];
    const float* mw   = (const float*)d_in[23];
    const float* mb   = (const float*)d_in[24];
    const float* ngp  = (const float*)d_in[25];
    const float* nbp  = (const float*)d_in[26];
    const float* sw   = (const float*)d_in[27];
    const float* sb   = (const float*)d_in[28];
    float* out = (float*)d_out;

    // workspace layout (floats); total 68,419,584 floats = 273.7 MB
    float* ws   = (float*)d_ws;
    float* wbr  = ws;                  // 14,155,776  (B,H,W,M2)
    float* wbi  = ws + 14155776;
    float* t_r  = ws + 28311552;       //  4,718,592  (B,M2,C,H)
    float* t_i  = ws + 33030144;
    float* hbr  = ws + 37748736;       //  3,538,944  (B,M2,H,M1)
    float* hbi  = ws + 41287680;
    float* t2r  = ws + 44826624;       //  1,179,648  (B,C,M1*M2)
    float* t2i  = ws + 46006272;
    float* prr  = ws + 47185920;       //  1,179,648  (B,O,M1*M2)
    float* pri  = ws + 48365568;
    float* rhr  = t_r;                 // reuse: t dead after k4
    float* rhi  = t_i;                 // (B,M2,H,O)
    float* yb   = ws + 49545216;       // 18,874,368  (B,O,H,W)

    k_mlp_w<<<dim3(4608), dim3(256), 0, stream>>>(x, wW0, wb0, wg0, wbe0,
                                                  wW1, wb1, wg1, wbe1, wW2, wb2, wbr, wbi);
    k2_t<<<dim3(1536), dim3(256), 0, stream>>>(x, wbr, wbi, t_r, t_i);
    k_mlp_h<<<dim3(1152), dim3(256), 0, stream>>>(t_r, hW0, hb0, hg0, hbe0,
                                                  hW1, hb1, hg1, hbe1, hW2, hb2, hbr, hbi);
    k4_t2<<<dim3(384), dim3(256), 0, stream>>>(t_r, t_i, hbr, hbi, t2r, t2i);
    k5_proc<<<dim3(288), dim3(256), 0, stream>>>(t2r, t2i, fr, fi, prr, pri);
    k6_rech<<<dim3(1536), dim3(256), 0, stream>>>(prr, pri, hbr, hbi, rhr, rhi);
    k7_rec<<<dim3(4608), dim3(256), 0, stream>>>(rhr, rhi, wbr, wbi, yb);
    k8_final<<<dim3(4608), dim3(256), 0, stream>>>(yb, x, mw, mb, ngp, nbp, sw, sb, out);
}

// Round 3
// 947.962 us; speedup vs baseline: 1.1359x; 1.1359x over previous
//
#include <hip/hip_runtime.h>
#include <math.h>

#define LN_EPS 1e-5f

typedef short bf16x8 __attribute__((ext_vector_type(8)));
typedef float f32x4  __attribute__((ext_vector_type(4)));

__device__ __forceinline__ float gelu_f(float v) {
    return 0.5f * v * (1.0f + erff(v * 0.70710678118654752f));
}
__device__ __forceinline__ unsigned short f2bf(float f) {
    unsigned u = __float_as_uint(f);
    return (unsigned short)((u + 0x7fffu + ((u >> 16) & 1u)) >> 16);
}
__device__ __forceinline__ float bf2f(unsigned short h) {
    return __uint_as_float(((unsigned)h) << 16);
}

// ===========================================================================
// K0: swizzle MLP weights into MFMA B-fragment order, split hi/lo bf16.
// For 16x16x32 bf16 MFMA: B[k][n] with n = lane&15, k = (lane>>4)*8 + j.
// Tile (nt,ks) = 16 cols x 32 rows.  Layout per tile: 128 uint4 =
// [hi: lane 0..63][lo: lane 0..63], each lane = 8 packed bf16 (16 B).
// Matrix bases (uint4): W0=0 (8 tiles), W1=1024, W2=2048 (12 tiles);
// h-MLP at +3584 (tiles 28..).
// ===========================================================================
__global__ __launch_bounds__(256) void k0_swizzle(
    const float* __restrict__ wW0, const float* __restrict__ wW1, const float* __restrict__ wW2,
    const float* __restrict__ hW0, const float* __restrict__ hW1, const float* __restrict__ hW2,
    uint4* __restrict__ dst)
{
    int mat = blockIdx.x;
    const float* W; int N, ntiles, base;
    switch (mat) {
      case 0: W=wW0; N=64; ntiles=8;  base=0;    break;
      case 1: W=wW1; N=64; ntiles=8;  base=1024; break;
      case 2: W=wW2; N=96; ntiles=12; base=2048; break;
      case 3: W=hW0; N=64; ntiles=8;  base=3584; break;
      case 4: W=hW1; N=64; ntiles=8;  base=4608; break;
      default:W=hW2; N=96; ntiles=12; base=5632; break;
    }
    int lane = threadIdx.x & 63;
    for (int t = threadIdx.x >> 6; t < ntiles; t += 4) {
        int nt = t >> 1, ks = t & 1;
        int n  = nt*16 + (lane & 15);
        int k0 = ks*32 + (lane >> 4)*8;
        unsigned hi[8], lo[8];
        #pragma unroll
        for (int j = 0; j < 8; ++j) {
            float v = W[(k0 + j)*N + n];
            unsigned short h = f2bf(v);
            hi[j] = h;
            lo[j] = f2bf(v - bf2f(h));
        }
        uint4 ph, pl;
        ph.x = hi[0] | (hi[1]<<16); ph.y = hi[2] | (hi[3]<<16);
        ph.z = hi[4] | (hi[5]<<16); ph.w = hi[6] | (hi[7]<<16);
        pl.x = lo[0] | (lo[1]<<16); pl.y = lo[2] | (lo[3]<<16);
        pl.z = lo[4] | (lo[5]<<16); pl.w = lo[6] | (lo[7]<<16);
        dst[base + t*128 + lane]      = ph;
        dst[base + t*128 + 64 + lane] = pl;
    }
}

// ===========================================================================
// Split-precision MFMA MLP.  Block = 256 thr = 4 waves; wave w owns 16
// positions (rows 16w..16w+15).  Activations in LDS, row stride 72 bf16.
// No __syncthreads anywhere: each wave reads only rows it wrote.
// ===========================================================================
template<int NT>
__device__ __forceinline__ void gemm64(
    const unsigned short* aHi, const unsigned short* aLo,
    const uint4* __restrict__ wsw, int tbase, int row, int quad, int lane,
    f32x4* acc)
{
    union U { uint4 u; bf16x8 b; };
    bf16x8 aH[2], aL[2];
    #pragma unroll
    for (int ks = 0; ks < 2; ++ks) {
        aH[ks] = *(const bf16x8*)&aHi[row*72 + ks*32 + quad*8];
        aL[ks] = *(const bf16x8*)&aLo[row*72 + ks*32 + quad*8];
    }
    #pragma unroll
    for (int nt = 0; nt < NT; ++nt) {
        f32x4 a = {0.f, 0.f, 0.f, 0.f};
        #pragma unroll
        for (int ks = 0; ks < 2; ++ks) {
            int t = tbase + nt*2 + ks;
            U bh, bl;
            bh.u = wsw[t*128 + lane];
            bl.u = wsw[t*128 + 64 + lane];
            a = __builtin_amdgcn_mfma_f32_16x16x32_bf16(aH[ks], bh.b, a, 0, 0, 0);
            a = __builtin_amdgcn_mfma_f32_16x16x32_bf16(aH[ks], bl.b, a, 0, 0, 0);
            a = __builtin_amdgcn_mfma_f32_16x16x32_bf16(aL[ks], bh.b, a, 0, 0, 0);
        }
        acc[nt] = a;
    }
}

__device__ __forceinline__ void ln_gelu_pass(
    f32x4* acc, const float* __restrict__ bias, const float* __restrict__ wrow,
    float coordBase, float coordScale,
    const float* __restrict__ gg, const float* __restrict__ bb,
    unsigned short* aHi, unsigned short* aLo, int rbase, int quad, int li)
{
    float vals[4][4];
    float s1[4] = {0,0,0,0}, s2[4] = {0,0,0,0};
    #pragma unroll
    for (int nt = 0; nt < 4; ++nt) {
        int col = nt*16 + li;
        float bv = bias[col];
        float br = wrow[col];
        #pragma unroll
        for (int rg = 0; rg < 4; ++rg) {
            float coord = (coordBase + (float)(rbase + quad*4 + rg)) * coordScale;
            float v = acc[nt][rg] + fmaf(coord, br, bv);
            vals[nt][rg] = v;
            s1[rg] += v;
            s2[rg] = fmaf(v, v, s2[rg]);
        }
    }
    #pragma unroll
    for (int d = 1; d < 16; d <<= 1) {
        #pragma unroll
        for (int rg = 0; rg < 4; ++rg) {
            s1[rg] += __shfl_xor(s1[rg], d, 64);
            s2[rg] += __shfl_xor(s2[rg], d, 64);
        }
    }
    #pragma unroll
    for (int nt = 0; nt < 4; ++nt) {
        int col = nt*16 + li;
        float gv = gg[col], bev = bb[col];
        #pragma unroll
        for (int rg = 0; rg < 4; ++rg) {
            float mu   = s1[rg] * 0.015625f;
            float rstd = rsqrtf(s2[rg]*0.015625f - mu*mu + LN_EPS);
            float v = gelu_f(fmaf((vals[nt][rg] - mu)*rstd, gv, bev));
            int r = rbase + quad*4 + rg;
            unsigned short hv = f2bf(v);
            aHi[r*72 + col] = hv;
            aLo[r*72 + col] = f2bf(v - bf2f(hv));
        }
    }
}

__device__ __forceinline__ void mlp_body(
    unsigned short* aHi, unsigned short* aLo,
    const uint4* __restrict__ wsw,
    const float* __restrict__ w0row,
    const float* __restrict__ b0, const float* __restrict__ g0, const float* __restrict__ be0,
    const float* __restrict__ b1, const float* __restrict__ g1, const float* __restrict__ be1,
    const float* __restrict__ b2,
    float coordBase,
    float* __restrict__ outR, float* __restrict__ outI, int pixBase)
{
    int tid = threadIdx.x;
    int wv = __builtin_amdgcn_readfirstlane(tid >> 6);
    int lane = tid & 63, li = lane & 15, quad = lane >> 4;
    int rbase = wv*16;
    int row = rbase + li;
    f32x4 acc[6];

    // layer 0: X @ W0 + (b0 + coord*W0[64,:]) -> LN -> GELU
    gemm64<4>(aHi, aLo, wsw, 0, row, quad, lane, acc);
    ln_gelu_pass(acc, b0, w0row, coordBase, 1.0f/191.0f, g0, be0, aHi, aLo, rbase, quad, li);
    // layer 1
    gemm64<4>(aHi, aLo, wsw, 8, row, quad, lane, acc);
    ln_gelu_pass(acc, b1, b1, 0.f, 0.f, g1, be1, aHi, aLo, rbase, quad, li);
    // layer 2: N=96, split into real/imag halves
    gemm64<6>(aHi, aLo, wsw, 16, row, quad, lane, acc);
    #pragma unroll
    for (int nt = 0; nt < 6; ++nt) {
        int j = nt*16 + li;
        float bv = b2[j];
        #pragma unroll
        for (int rg = 0; rg < 4; ++rg) {
            float v = acc[nt][rg] + bv;
            int pix = pixBase + rbase + quad*4 + rg;
            if (nt < 3) outR[pix*48 + j]        = v;
            else        outI[pix*48 + (j - 48)] = v;
        }
    }
}

// K1: W-basis MLP.  grid 4608 = (b*192+h)*3 + wq.
__global__ __launch_bounds__(256) void k1_mlp_w(
    const float* __restrict__ x, const float* __restrict__ W0full,
    const float* __restrict__ b0, const float* __restrict__ g0, const float* __restrict__ be0,
    const float* __restrict__ b1, const float* __restrict__ g1, const float* __restrict__ be1,
    const float* __restrict__ b2,
    const uint4* __restrict__ wsw,
    float* __restrict__ wb_r, float* __restrict__ wb_i)
{
    __shared__ unsigned short aHi[64*72];
    __shared__ unsigned short aLo[64*72];
    int tid = threadIdx.x;
    int wv = __builtin_amdgcn_readfirstlane(tid >> 6);
    int lane = tid & 63, li = lane & 15, quad = lane >> 4;
    int wq = blockIdx.x % 3;
    int bh = blockIdx.x / 3;
    int b = bh / 192, h = bh % 192;
    int w0 = wq * 64;
    int r = wv*16 + li;
    #pragma unroll
    for (int cc = 0; cc < 16; ++cc) {
        int c = cc*4 + quad;
        float v = x[((b*64 + c)*192 + h)*192 + (w0 + r)];
        unsigned short hv = f2bf(v);
        aHi[r*72 + c] = hv;
        aLo[r*72 + c] = f2bf(v - bf2f(hv));
    }
    mlp_body(aHi, aLo, wsw, W0full + 64*64, b0, g0, be0, b1, g1, be1, b2,
             (float)w0, wb_r, wb_i, bh*192 + w0);
}

// K3: H-basis MLP.  grid 1152 = (b*48+m)*3 + hq.
__global__ __launch_bounds__(256) void k3_mlp_h(
    const float* __restrict__ t_r, const float* __restrict__ W0full,
    const float* __restrict__ b0, const float* __restrict__ g0, const float* __restrict__ be0,
    const float* __restrict__ b1, const float* __restrict__ g1, const float* __restrict__ be1,
    const float* __restrict__ b2,
    const uint4* __restrict__ wsw,
    float* __restrict__ hb_r, float* __restrict__ hb_i)
{
    __shared__ unsigned short aHi[64*72];
    __shared__ unsigned short aLo[64*72];
    int tid = threadIdx.x;
    int wv = __builtin_amdgcn_readfirstlane(tid >> 6);
    int lane = tid & 63, li = lane & 15, quad = lane >> 4;
    int hq = blockIdx.x % 3;
    int bm = blockIdx.x / 3;
    int h0 = hq * 64;
    int r = wv*16 + li;
    #pragma unroll
    for (int cc = 0; cc < 16; ++cc) {
        int c = cc*4 + quad;
        float v = t_r[(bm*64 + c)*192 + (h0 + r)];
        unsigned short hv = f2bf(v);
        aHi[r*72 + c] = hv;
        aLo[r*72 + c] = f2bf(v - bf2f(hv));
    }
    mlp_body(aHi, aLo, wsw, W0full + 64*64, b0, g0, be0, b1, g1, be1, b2,
             (float)h0, hb_r, hb_i, bm*192 + h0);
}

// K2: t[b,c,h,m] = sum_w x[b,c,h,w]*wb[b,h,w,m].  grid 1536 = b*192+h.
// t stored (B,M2,C,H) for coalesced downstream reads.
__global__ __launch_bounds__(256) void k2_t(
    const float* __restrict__ x,
    const float* __restrict__ wb_r, const float* __restrict__ wb_i,
    float* __restrict__ t_r, float* __restrict__ t_i)
{
    __shared__ float xs[64*33];
    __shared__ float wbs[32*96];
    int bh = blockIdx.x;                  // b*192 + h
    int b = bh / 192, h = bh % 192;
    int tid = threadIdx.x;
    int c = tid >> 2, mg = tid & 3;
    float accr[12], acci[12];
    #pragma unroll
    for (int k = 0; k < 12; ++k) { accr[k] = 0.f; acci[k] = 0.f; }
    for (int w0 = 0; w0 < 192; w0 += 32) {
        for (int idx = tid; idx < 2048; idx += 256) {
            int cc = idx >> 5, ww = idx & 31;
            xs[cc*33 + ww] = x[((b*64 + cc)*192 + h)*192 + (w0 + ww)];
        }
        for (int idx = tid; idx < 1536; idx += 256) {
            int ww = idx / 48, mm = idx % 48;
            int g = (bh*192 + (w0 + ww))*48 + mm;
            wbs[ww*96 + mm]      = wb_r[g];
            wbs[ww*96 + 48 + mm] = wb_i[g];
        }
        __syncthreads();
        for (int ww = 0; ww < 32; ++ww) {
            float xv = xs[c*33 + ww];
            const float4* wr4 = (const float4*)(wbs + ww*96 + mg*12);
            const float4* wi4 = (const float4*)(wbs + ww*96 + 48 + mg*12);
            #pragma unroll
            for (int q = 0; q < 3; ++q) {
                float4 wr = wr4[q], wi = wi4[q];
                accr[4*q+0] = fmaf(xv, wr.x, accr[4*q+0]);
                accr[4*q+1] = fmaf(xv, wr.y, accr[4*q+1]);
                accr[4*q+2] = fmaf(xv, wr.z, accr[4*q+2]);
                accr[4*q+3] = fmaf(xv, wr.w, accr[4*q+3]);
                acci[4*q+0] = fmaf(xv, wi.x, acci[4*q+0]);
                acci[4*q+1] = fmaf(xv, wi.y, acci[4*q+1]);
                acci[4*q+2] = fmaf(xv, wi.z, acci[4*q+2]);
                acci[4*q+3] = fmaf(xv, wi.w, acci[4*q+3]);
            }
        }
        __syncthreads();
    }
    #pragma unroll
    for (int k = 0; k < 12; ++k) {
        int m = mg*12 + k;
        int a = ((b*48 + m)*64 + c)*192 + h;
        t_r[a] = accr[k];
        t_i[a] = acci[k];
    }
}

// K4: t2[b,c,n,m] = sum_h t[b,c,h,m]*hb[b,m,h,n].  grid 384 = b*48+m.
__global__ __launch_bounds__(256) void k4_t2(
    const float* __restrict__ t_r, const float* __restrict__ t_i,
    const float* __restrict__ hb_r, const float* __restrict__ hb_i,
    float* __restrict__ t2_r, float* __restrict__ t2_i)
{
    __shared__ float tsr[64*33], tsi[64*33];
    __shared__ float hbs[32*96];
    int bm = blockIdx.x;                  // b*48 + m
    int b = bm / 48, m = bm % 48;
    int tid = threadIdx.x;
    int c = tid >> 2, ng = tid & 3;
    float ar[12], ai[12];
    #pragma unroll
    for (int k = 0; k < 12; ++k) { ar[k] = 0.f; ai[k] = 0.f; }
    for (int h0 = 0; h0 < 192; h0 += 32) {
        for (int idx = tid; idx < 2048; idx += 256) {
            int cc = idx >> 5, hh = idx & 31;
            int g = (bm*64 + cc)*192 + (h0 + hh);
            tsr[cc*33 + hh] = t_r[g];
            tsi[cc*33 + hh] = t_i[g];
        }
        for (int idx = tid; idx < 1536; idx += 256) {
            int hh = idx / 48, nn = idx % 48;
            int g = (bm*192 + (h0 + hh))*48 + nn;
            hbs[hh*96 + nn]      = hb_r[g];
            hbs[hh*96 + 48 + nn] = hb_i[g];
        }
        __syncthreads();
        for (int hh = 0; hh < 32; ++hh) {
            float tr = tsr[c*33 + hh];
            float ti = tsi[c*33 + hh];
            const float4* hr4 = (const float4*)(hbs + hh*96 + ng*12);
            const float4* hi4 = (const float4*)(hbs + hh*96 + 48 + ng*12);
            #pragma unroll
            for (int q = 0; q < 3; ++q) {
                float4 hr = hr4[q], hi = hi4[q];
                ar[4*q+0] = fmaf(tr, hr.x, fmaf(-ti, hi.x, ar[4*q+0]));
                ai[4*q+0] = fmaf(tr, hi.x, fmaf( ti, hr.x, ai[4*q+0]));
                ar[4*q+1] = fmaf(tr, hr.y, fmaf(-ti, hi.y, ar[4*q+1]));
                ai[4*q+1] = fmaf(tr, hi.y, fmaf( ti, hr.y, ai[4*q+1]));
                ar[4*q+2] = fmaf(tr, hr.z, fmaf(-ti, hi.z, ar[4*q+2]));
                ai[4*q+2] = fmaf(tr, hi.z, fmaf( ti, hr.z, ai[4*q+2]));
                ar[4*q+3] = fmaf(tr, hr.w, fmaf(-ti, hi.w, ar[4*q+3]));
                ai[4*q+3] = fmaf(tr, hi.w, fmaf( ti, hr.w, ai[4*q+3]));
            }
        }
        __syncthreads();
    }
    #pragma unroll
    for (int k = 0; k < 12; ++k) {
        int n = ng*12 + k;
        int a = (b*64 + c)*2304 + n*48 + m;
        t2_r[a] = ar[k];
        t2_i[a] = ai[k];
    }
}

// K5: proc[b,o,nm] = sum_i t2[b,i,nm]*Wf[o,i,nm].  grid 288 = 32 og x 9 chunks.
__global__ __launch_bounds__(256) void k5_proc(
    const float* __restrict__ t2_r, const float* __restrict__ t2_i,
    const float* __restrict__ fr, const float* __restrict__ fi,
    float* __restrict__ proc_r, float* __restrict__ proc_i)
{
    int og = blockIdx.x & 31;
    int ch = blockIdx.x >> 5;
    int nm = ch*256 + threadIdx.x;
    int o0 = og*2;
    float p0r[8], p0i[8], p1r[8], p1i[8];
    #pragma unroll
    for (int bb = 0; bb < 8; ++bb) { p0r[bb]=0.f; p0i[bb]=0.f; p1r[bb]=0.f; p1i[bb]=0.f; }
    for (int i = 0; i < 64; ++i) {
        float w0r = fr[(o0*64 + i)*2304 + nm];
        float w0i = fi[(o0*64 + i)*2304 + nm];
        float w1r = fr[((o0+1)*64 + i)*2304 + nm];
        float w1i = fi[((o0+1)*64 + i)*2304 + nm];
        #pragma unroll
        for (int bb = 0; bb < 8; ++bb) {
            float tr = t2_r[(bb*64 + i)*2304 + nm];
            float ti = t2_i[(bb*64 + i)*2304 + nm];
            p0r[bb] = fmaf(tr, w0r, fmaf(-ti, w0i, p0r[bb]));
            p0i[bb] = fmaf(tr, w0i, fmaf( ti, w0r, p0i[bb]));
            p1r[bb] = fmaf(tr, w1r, fmaf(-ti, w1i, p1r[bb]));
            p1i[bb] = fmaf(tr, w1i, fmaf( ti, w1r, p1i[bb]));
        }
    }
    #pragma unroll
    for (int bb = 0; bb < 8; ++bb) {
        proc_r[(bb*64 + o0)*2304 + nm]     = p0r[bb];
        proc_i[(bb*64 + o0)*2304 + nm]     = p0i[bb];
        proc_r[(bb*64 + o0 + 1)*2304 + nm] = p1r[bb];
        proc_i[(bb*64 + o0 + 1)*2304 + nm] = p1i[bb];
    }
}

// K6: rec_h[b,o,h,m] = sum_n proc[b,o,n,m]*conj(hb)[b,m,h,n].
// grid 1536 = (b*48+m)*4 + hq.  rec_h stored (B,M2,H,O).
__global__ __launch_bounds__(256) void k6_rech(
    const float* __restrict__ proc_r, const float* __restrict__ proc_i,
    const float* __restrict__ hb_r, const float* __restrict__ hb_i,
    float* __restrict__ rh_r, float* __restrict__ rh_i)
{
    __shared__ float psr[64*49], psi[64*49];
    __shared__ float hsr[48*52], hsi[48*52];
    int hq = blockIdx.x & 3;
    int bm = blockIdx.x >> 2;             // b*48 + m
    int b = bm / 48, m = bm % 48;
    int tid = threadIdx.x;
    int o = tid & 63, hg = tid >> 6;
    for (int idx = tid; idx < 3072; idx += 256) {
        int oo = idx / 48, nn = idx % 48;
        int g = (b*64 + oo)*2304 + nn*48 + m;
        psr[oo*49 + nn] = proc_r[g];
        psi[oo*49 + nn] = proc_i[g];
    }
    for (int idx = tid; idx < 2304; idx += 256) {
        int hh = idx / 48, nn = idx % 48;
        int g = (bm*192 + hq*48 + hh)*48 + nn;
        hsr[hh*52 + nn] = hb_r[g];
        hsi[hh*52 + nn] = hb_i[g];
    }
    __syncthreads();
    float accr[12], acci[12];
    #pragma unroll
    for (int j = 0; j < 12; ++j) { accr[j]=0.f; acci[j]=0.f; }
    for (int n4 = 0; n4 < 48; n4 += 4) {
        float prv[4], piv[4];
        #pragma unroll
        for (int q = 0; q < 4; ++q) {
            prv[q] = psr[o*49 + n4 + q];
            piv[q] = psi[o*49 + n4 + q];
        }
        #pragma unroll
        for (int j = 0; j < 12; ++j) {
            const float4 hr = *(const float4*)(hsr + (hg*12 + j)*52 + n4);
            const float4 hi = *(const float4*)(hsi + (hg*12 + j)*52 + n4);
            accr[j] += prv[0]*hr.x + piv[0]*hi.x
                     + prv[1]*hr.y + piv[1]*hi.y
                     + prv[2]*hr.z + piv[2]*hi.z
                     + prv[3]*hr.w + piv[3]*hi.w;
            acci[j] += piv[0]*hr.x - prv[0]*hi.x
                     + piv[1]*hr.y - prv[1]*hi.y
                     + piv[2]*hr.z - prv[2]*hi.z
                     + piv[3]*hr.w - prv[3]*hi.w;
        }
    }
    #pragma unroll
    for (int j = 0; j < 12; ++j) {
        int h = hq*48 + hg*12 + j;
        int a = (bm*192 + h)*64 + o;
        rh_r[a] = accr[j];
        rh_i[a] = acci[j];
    }
}

// K7: y[b,o,h,w] = (1/(H*W)) * sum_m rec_h[b,o,h,m]*conj(wb)[b,h,w,m] (real).
// grid 4608 = (b*192+h)*3 + wq.
__global__ __launch_bounds__(256) void k7_rec(
    const float* __restrict__ rh_r, const float* __restrict__ rh_i,
    const float* __restrict__ wb_r, const float* __restrict__ wb_i,
    float* __restrict__ y)
{
    __shared__ float asr[48*64], asi[48*64];
    __shared__ float wsr[64*49], wsi[64*49];
    int wq = blockIdx.x % 3;
    int bh = blockIdx.x / 3;              // b*192 + h
    int b = bh / 192, h = bh % 192;
    int tid = threadIdx.x;
    int w_l = tid & 63, og = tid >> 6;
    for (int idx = tid; idx < 3072; idx += 256) {
        int mm = idx >> 6, oo = idx & 63;
        int g = ((b*48 + mm)*192 + h)*64 + oo;
        asr[idx] = rh_r[g];
        asi[idx] = rh_i[g];
    }
    for (int idx = tid; idx < 3072; idx += 256) {
        int ww = idx / 48, mm = idx % 48;
        int g = (bh*192 + wq*64 + ww)*48 + mm;
        wsr[ww*49 + mm] = wb_r[g];
        wsi[ww*49 + mm] = wb_i[g];
    }
    __syncthreads();
    float acc[16];
    #pragma unroll
    for (int k = 0; k < 16; ++k) acc[k] = 0.f;
    for (int m = 0; m < 48; ++m) {
        float wr = wsr[w_l*49 + m];
        float wi = wsi[w_l*49 + m];
        #pragma unroll
        for (int q = 0; q < 4; ++q) {
            const float4 arv = *(const float4*)(asr + m*64 + og*16 + q*4);
            const float4 aiv = *(const float4*)(asi + m*64 + og*16 + q*4);
            acc[4*q+0] = fmaf(arv.x, wr, fmaf(aiv.x, wi, acc[4*q+0]));
            acc[4*q+1] = fmaf(arv.y, wr, fmaf(aiv.y, wi, acc[4*q+1]));
            acc[4*q+2] = fmaf(arv.z, wr, fmaf(aiv.z, wi, acc[4*q+2]));
            acc[4*q+3] = fmaf(arv.w, wr, fmaf(aiv.w, wi, acc[4*q+3]));
        }
    }
    const float s = 1.0f / 36864.0f;
    #pragma unroll
    for (int k = 0; k < 16; ++k) {
        int o = og*16 + k;
        y[((b*64 + o)*192 + h)*192 + wq*64 + w_l] = acc[k] * s;
    }
}

// K8: mixer GEMM + channel-LN + GELU + shortcut GEMM + GELU.  grid 4608.
__global__ __launch_bounds__(256) void k8_final(
    const float* __restrict__ y, const float* __restrict__ x,
    const float* __restrict__ mw, const float* __restrict__ mb,
    const float* __restrict__ nrm_g, const float* __restrict__ nrm_b,
    const float* __restrict__ sw, const float* __restrict__ sb,
    float* __restrict__ out)
{
    __shared__ float ys[64*65], xs[64*65];
    __shared__ float mws[64*68], sws[64*68];
    __shared__ float red[512];
    int wq = blockIdx.x % 3;
    int bh = blockIdx.x / 3;
    int b = bh / 192, h = bh % 192;
    int tid = threadIdx.x;
    int w_l = tid & 63, og = tid >> 6;
    int w0 = wq * 64;
    for (int cc = og; cc < 64; cc += 4) {
        int g = ((b*64 + cc)*192 + h)*192 + w0 + w_l;
        ys[cc*65 + w_l] = y[g];
        xs[cc*65 + w_l] = x[g];
    }
    for (int idx = tid; idx < 4096; idx += 256) {
        int oo = idx >> 6, cc = idx & 63;
        mws[cc*68 + oo] = mw[idx];
        sws[cc*68 + oo] = sw[idx];
    }
    __syncthreads();
    float accy[16], accs[16];
    #pragma unroll
    for (int k = 0; k < 16; ++k) { accy[k]=0.f; accs[k]=0.f; }
    for (int cc = 0; cc < 64; ++cc) {
        float yv = ys[cc*65 + w_l];
        float xv = xs[cc*65 + w_l];
        #pragma unroll
        for (int q = 0; q < 4; ++q) {
            const float4 m4 = *(const float4*)(mws + cc*68 + og*16 + q*4);
            const float4 s4 = *(const float4*)(sws + cc*68 + og*16 + q*4);
            accy[4*q+0] = fmaf(yv, m4.x, accy[4*q+0]);
            accy[4*q+1] = fmaf(yv, m4.y, accy[4*q+1]);
            accy[4*q+2] = fmaf(yv, m4.z, accy[4*q+2]);
            accy[4*q+3] = fmaf(yv, m4.w, accy[4*q+3]);
            accs[4*q+0] = fmaf(xv, s4.x, accs[4*q+0]);
            accs[4*q+1] = fmaf(xv, s4.y, accs[4*q+1]);
            accs[4*q+2] = fmaf(xv, s4.z, accs[4*q+2]);
            accs[4*q+3] = fmaf(xv, s4.w, accs[4*q+3]);
        }
    }
    float s1 = 0.f, s2 = 0.f;
    #pragma unroll
    for (int k = 0; k < 16; ++k) {
        int o = og*16 + k;
        accy[k] += mb[o];
        s1 += accy[k];
        s2 = fmaf(accy[k], accy[k], s2);
    }
    red[og*64 + w_l]       = s1;
    red[256 + og*64 + w_l] = s2;
    __syncthreads();
    float mu = (red[w_l] + red[64+w_l] + red[128+w_l] + red[192+w_l]) * 0.015625f;
    float ms = (red[256+w_l] + red[320+w_l] + red[384+w_l] + red[448+w_l]) * 0.015625f;
    float rstd = rsqrtf(ms - mu*mu + LN_EPS);
    #pragma unroll
    for (int k = 0; k < 16; ++k) {
        int o = og*16 + k;
        float v = (accy[k] - mu) * rstd * nrm_g[o] + nrm_b[o];
        v = gelu_f(v);
        float sc = accs[k] + sb[o];
        out[((b*64 + o)*192 + h)*192 + w0 + w_l] = gelu_f(v + sc);
    }
}

extern "C" void kernel_launch(void* const* d_in, const int* in_sizes, int n_in,
                              void* d_out, int out_size, void* d_ws, size_t ws_size,
                              hipStream_t stream)
{
    (void)in_sizes; (void)n_in; (void)out_size; (void)ws_size;
    const float* x    = (const float*)d_in[0];
    const float* wW0  = (const float*)d_in[1];
    const float* wb0  = (const float*)d_in[2];
    const float* wg0  = (const float*)d_in[3];
    const float* wbe0 = (const float*)d_in[4];
    const float* wW1  = (const float*)d_in[5];
    const float* wb1  = (const float*)d_in[6];
    const float* wg1  = (const float*)d_in[7];
    const float* wbe1 = (const float*)d_in[8];
    const float* wW2  = (const float*)d_in[9];
    const float* wb2  = (const float*)d_in[10];
    const float* hW0  = (const float*)d_in[11];
    const float* hb0  = (const float*)d_in[12];
    const float* hg0  = (const float*)d_in[13];
    const float* hbe0 = (const float*)d_in[14];
    const float* hW1  = (const float*)d_in[15];
    const float* hb1  = (const float*)d_in[16];
    const float* hg1  = (const float*)d_in[17];
    const float* hbe1 = (const float*)d_in[18];
    const float* hW2  = (const float*)d_in[19];
    const float* hb2  = (const float*)d_in[20];
    const float* fr   = (const float*)d_in[21];
    const float* fi   = (const float*)d_in[22];
    const float* mw   = (const float*)d_in[23];
    const float* mb   = (const float*)d_in[24];
    const float* ngp  = (const float*)d_in[25];
    const float* nbp  = (const float*)d_in[26];
    const float* sw   = (const float*)d_in[27];
    const float* sb   = (const float*)d_in[28];
    float* out = (float*)d_out;

    // workspace layout (floats); total 68,419,584 floats = 273.7 MB
    float* ws   = (float*)d_ws;
    float* wbr  = ws;                  // 14,155,776  (B,H,W,M2)
    float* wbi  = ws + 14155776;
    float* t_r  = ws + 28311552;       //  4,718,592  (B,M2,C,H)
    float* t_i  = ws + 33030144;
    float* hbr  = ws + 37748736;       //  3,538,944  (B,M2,H,M1)
    float* hbi  = ws + 41287680;
    float* t2r  = ws + 44826624;       //  1,179,648  (B,C,M1*M2)
    float* t2i  = ws + 46006272;
    float* prr  = ws + 47185920;       //  1,179,648  (B,O,M1*M2)
    float* pri  = ws + 48365568;
    float* rhr  = t_r;                 // reuse: t dead after k4
    float* rhi  = t_i;                 // (B,M2,H,O)
    float* yb   = ws + 49545216;       // 18,874,368  (B,O,H,W)
    // swizzled MLP weights live in the yb region (dead until k7; weights
    // are consumed by k1/k3 which run before k7 writes y).  7168 uint4.
    uint4* wsw  = (uint4*)yb;

    k0_swizzle<<<dim3(6), dim3(256), 0, stream>>>(wW0, wW1, wW2, hW0, hW1, hW2, wsw);
    k1_mlp_w<<<dim3(4608), dim3(256), 0, stream>>>(x, wW0, wb0, wg0, wbe0,
                                                   wb1, wg1, wbe1, wb2, wsw, wbr, wbi);
    k2_t<<<dim3(1536), dim3(256), 0, stream>>>(x, wbr, wbi, t_r, t_i);
    // NOTE: h-MLP swizzled weights live at uint4 offset 3584 (tile 28) —
    // round-2 bug was passing base wsw here (h-MLP ran with w-MLP weights).
    k3_mlp_h<<<dim3(1152), dim3(256), 0, stream>>>(t_r, hW0, hb0, hg0, hbe0,
                                                   hb1, hg1, hbe1, hb2, wsw + 3584, hbr, hbi);
    k4_t2<<<dim3(384), dim3(256), 0, stream>>>(t_r, t_i, hbr, hbi, t2r, t2i);
    k5_proc<<<dim3(288), dim3(256), 0, stream>>>(t2r, t2i, fr, fi, prr, pri);
    k6_rech<<<dim3(1536), dim3(256), 0, stream>>>(prr, pri, hbr, hbi, rhr, rhi);
    k7_rec<<<dim3(4608), dim3(256), 0, stream>>>(rhr, rhi, wbr, wbi, yb);
    k8_final<<<dim3(4608), dim3(256), 0, stream>>>(yb, x, mw, mb, ngp, nbp, sw, sb, out);
}

// Round 4
// 894.711 us; speedup vs baseline: 1.2035x; 1.0595x over previous
//
#include <hip/hip_runtime.h>
#include <math.h>

#define LN_EPS 1e-5f

typedef short bf16x8 __attribute__((ext_vector_type(8)));
typedef float f32x4  __attribute__((ext_vector_type(4)));

__device__ __forceinline__ float gelu_f(float v) {
    return 0.5f * v * (1.0f + erff(v * 0.70710678118654752f));
}
__device__ __forceinline__ unsigned short f2bf(float f) {
    unsigned u = __float_as_uint(f);
    return (unsigned short)((u + 0x7fffu + ((u >> 16) & 1u)) >> 16);
}
__device__ __forceinline__ float bf2f(unsigned short h) {
    return __uint_as_float(((unsigned)h) << 16);
}

// ===========================================================================
// K0: swizzle MLP weights into MFMA B-fragment order, split hi/lo bf16.
// ===========================================================================
__global__ __launch_bounds__(256) void k0_swizzle(
    const float* __restrict__ wW0, const float* __restrict__ wW1, const float* __restrict__ wW2,
    const float* __restrict__ hW0, const float* __restrict__ hW1, const float* __restrict__ hW2,
    uint4* __restrict__ dst)
{
    int mat = blockIdx.x;
    const float* W; int N, ntiles, base;
    switch (mat) {
      case 0: W=wW0; N=64; ntiles=8;  base=0;    break;
      case 1: W=wW1; N=64; ntiles=8;  base=1024; break;
      case 2: W=wW2; N=96; ntiles=12; base=2048; break;
      case 3: W=hW0; N=64; ntiles=8;  base=3584; break;
      case 4: W=hW1; N=64; ntiles=8;  base=4608; break;
      default:W=hW2; N=96; ntiles=12; base=5632; break;
    }
    int lane = threadIdx.x & 63;
    for (int t = threadIdx.x >> 6; t < ntiles; t += 4) {
        int nt = t >> 1, ks = t & 1;
        int n  = nt*16 + (lane & 15);
        int k0 = ks*32 + (lane >> 4)*8;
        unsigned hi[8], lo[8];
        #pragma unroll
        for (int j = 0; j < 8; ++j) {
            float v = W[(k0 + j)*N + n];
            unsigned short h = f2bf(v);
            hi[j] = h;
            lo[j] = f2bf(v - bf2f(h));
        }
        uint4 ph, pl;
        ph.x = hi[0] | (hi[1]<<16); ph.y = hi[2] | (hi[3]<<16);
        ph.z = hi[4] | (hi[5]<<16); ph.w = hi[6] | (hi[7]<<16);
        pl.x = lo[0] | (lo[1]<<16); pl.y = lo[2] | (lo[3]<<16);
        pl.z = lo[4] | (lo[5]<<16); pl.w = lo[6] | (lo[7]<<16);
        dst[base + t*128 + lane]      = ph;
        dst[base + t*128 + 64 + lane] = pl;
    }
}

// ===========================================================================
// Split-precision MFMA MLP (4 waves x 16 positions, no __syncthreads).
// ===========================================================================
template<int NT>
__device__ __forceinline__ void gemm64(
    const unsigned short* aHi, const unsigned short* aLo,
    const uint4* __restrict__ wsw, int tbase, int row, int quad, int lane,
    f32x4* acc)
{
    union U { uint4 u; bf16x8 b; };
    bf16x8 aH[2], aL[2];
    #pragma unroll
    for (int ks = 0; ks < 2; ++ks) {
        aH[ks] = *(const bf16x8*)&aHi[row*72 + ks*32 + quad*8];
        aL[ks] = *(const bf16x8*)&aLo[row*72 + ks*32 + quad*8];
    }
    #pragma unroll
    for (int nt = 0; nt < NT; ++nt) {
        f32x4 a = {0.f, 0.f, 0.f, 0.f};
        #pragma unroll
        for (int ks = 0; ks < 2; ++ks) {
            int t = tbase + nt*2 + ks;
            U bh, bl;
            bh.u = wsw[t*128 + lane];
            bl.u = wsw[t*128 + 64 + lane];
            a = __builtin_amdgcn_mfma_f32_16x16x32_bf16(aH[ks], bh.b, a, 0, 0, 0);
            a = __builtin_amdgcn_mfma_f32_16x16x32_bf16(aH[ks], bl.b, a, 0, 0, 0);
            a = __builtin_amdgcn_mfma_f32_16x16x32_bf16(aL[ks], bh.b, a, 0, 0, 0);
        }
        acc[nt] = a;
    }
}

__device__ __forceinline__ void ln_gelu_pass(
    f32x4* acc, const float* __restrict__ bias, const float* __restrict__ wrow,
    float coordBase, float coordScale,
    const float* __restrict__ gg, const float* __restrict__ bb,
    unsigned short* aHi, unsigned short* aLo, int rbase, int quad, int li)
{
    float vals[4][4];
    float s1[4] = {0,0,0,0}, s2[4] = {0,0,0,0};
    #pragma unroll
    for (int nt = 0; nt < 4; ++nt) {
        int col = nt*16 + li;
        float bv = bias[col];
        float br = wrow[col];
        #pragma unroll
        for (int rg = 0; rg < 4; ++rg) {
            float coord = (coordBase + (float)(rbase + quad*4 + rg)) * coordScale;
            float v = acc[nt][rg] + fmaf(coord, br, bv);
            vals[nt][rg] = v;
            s1[rg] += v;
            s2[rg] = fmaf(v, v, s2[rg]);
        }
    }
    #pragma unroll
    for (int d = 1; d < 16; d <<= 1) {
        #pragma unroll
        for (int rg = 0; rg < 4; ++rg) {
            s1[rg] += __shfl_xor(s1[rg], d, 64);
            s2[rg] += __shfl_xor(s2[rg], d, 64);
        }
    }
    #pragma unroll
    for (int nt = 0; nt < 4; ++nt) {
        int col = nt*16 + li;
        float gv = gg[col], bev = bb[col];
        #pragma unroll
        for (int rg = 0; rg < 4; ++rg) {
            float mu   = s1[rg] * 0.015625f;
            float rstd = rsqrtf(s2[rg]*0.015625f - mu*mu + LN_EPS);
            float v = gelu_f(fmaf((vals[nt][rg] - mu)*rstd, gv, bev));
            int r = rbase + quad*4 + rg;
            unsigned short hv = f2bf(v);
            aHi[r*72 + col] = hv;
            aLo[r*72 + col] = f2bf(v - bf2f(hv));
        }
    }
}

__device__ __forceinline__ void mlp_body(
    unsigned short* aHi, unsigned short* aLo,
    const uint4* __restrict__ wsw,
    const float* __restrict__ w0row,
    const float* __restrict__ b0, const float* __restrict__ g0, const float* __restrict__ be0,
    const float* __restrict__ b1, const float* __restrict__ g1, const float* __restrict__ be1,
    const float* __restrict__ b2,
    float coordBase,
    float* __restrict__ outR, float* __restrict__ outI, int pixBase)
{
    int tid = threadIdx.x;
    int wv = __builtin_amdgcn_readfirstlane(tid >> 6);
    int lane = tid & 63, li = lane & 15, quad = lane >> 4;
    int rbase = wv*16;
    int row = rbase + li;
    f32x4 acc[6];

    gemm64<4>(aHi, aLo, wsw, 0, row, quad, lane, acc);
    ln_gelu_pass(acc, b0, w0row, coordBase, 1.0f/191.0f, g0, be0, aHi, aLo, rbase, quad, li);
    gemm64<4>(aHi, aLo, wsw, 8, row, quad, lane, acc);
    ln_gelu_pass(acc, b1, b1, 0.f, 0.f, g1, be1, aHi, aLo, rbase, quad, li);
    gemm64<6>(aHi, aLo, wsw, 16, row, quad, lane, acc);
    #pragma unroll
    for (int nt = 0; nt < 6; ++nt) {
        int j = nt*16 + li;
        float bv = b2[j];
        #pragma unroll
        for (int rg = 0; rg < 4; ++rg) {
            float v = acc[nt][rg] + bv;
            int pix = pixBase + rbase + quad*4 + rg;
            if (nt < 3) outR[pix*48 + j]        = v;
            else        outI[pix*48 + (j - 48)] = v;
        }
    }
}

// K1: W-basis MLP.  grid 4608 = (b*192+h)*3 + wq.
__global__ __launch_bounds__(256) void k1_mlp_w(
    const float* __restrict__ x, const float* __restrict__ W0full,
    const float* __restrict__ b0, const float* __restrict__ g0, const float* __restrict__ be0,
    const float* __restrict__ b1, const float* __restrict__ g1, const float* __restrict__ be1,
    const float* __restrict__ b2,
    const uint4* __restrict__ wsw,
    float* __restrict__ wb_r, float* __restrict__ wb_i)
{
    __shared__ unsigned short aHi[64*72];
    __shared__ unsigned short aLo[64*72];
    int tid = threadIdx.x;
    int wv = __builtin_amdgcn_readfirstlane(tid >> 6);
    int lane = tid & 63, li = lane & 15, quad = lane >> 4;
    int wq = blockIdx.x % 3;
    int bh = blockIdx.x / 3;
    int b = bh / 192, h = bh % 192;
    int w0 = wq * 64;
    int r = wv*16 + li;
    #pragma unroll
    for (int cc = 0; cc < 16; ++cc) {
        int c = cc*4 + quad;
        float v = x[((b*64 + c)*192 + h)*192 + (w0 + r)];
        unsigned short hv = f2bf(v);
        aHi[r*72 + c] = hv;
        aLo[r*72 + c] = f2bf(v - bf2f(hv));
    }
    mlp_body(aHi, aLo, wsw, W0full + 64*64, b0, g0, be0, b1, g1, be1, b2,
             (float)w0, wb_r, wb_i, bh*192 + w0);
}

// K3: H-basis MLP.  grid 1152 = (b*48+m)*3 + hq.
// t layout is now (B,H,C,M2): t_r[((b*192+h)*64+c)*48+m]  (scattered reads,
// L3-served; the producer k2 writes coalesced instead).
__global__ __launch_bounds__(256) void k3_mlp_h(
    const float* __restrict__ t_r, const float* __restrict__ W0full,
    const float* __restrict__ b0, const float* __restrict__ g0, const float* __restrict__ be0,
    const float* __restrict__ b1, const float* __restrict__ g1, const float* __restrict__ be1,
    const float* __restrict__ b2,
    const uint4* __restrict__ wsw,
    float* __restrict__ hb_r, float* __restrict__ hb_i)
{
    __shared__ unsigned short aHi[64*72];
    __shared__ unsigned short aLo[64*72];
    int tid = threadIdx.x;
    int wv = __builtin_amdgcn_readfirstlane(tid >> 6);
    int lane = tid & 63, li = lane & 15, quad = lane >> 4;
    int hq = blockIdx.x % 3;
    int bm = blockIdx.x / 3;
    int b = bm / 48, m = bm % 48;
    int h0 = hq * 64;
    int r = wv*16 + li;
    #pragma unroll
    for (int cc = 0; cc < 16; ++cc) {
        int c = cc*4 + quad;
        float v = t_r[((b*192 + h0 + r)*64 + c)*48 + m];
        unsigned short hv = f2bf(v);
        aHi[r*72 + c] = hv;
        aLo[r*72 + c] = f2bf(v - bf2f(hv));
    }
    mlp_body(aHi, aLo, wsw, W0full + 64*64, b0, g0, be0, b1, g1, be1, b2,
             (float)h0, hb_r, hb_i, bm*192 + h0);
}

// K2: t[b,c,h,m] = sum_w x[b,c,h,w]*wb[b,h,w,m].  grid 1536 = b*192+h.
// t stored (B,H,C,M2) -> fully coalesced stores (round-3 fix: the old
// (B,M2,C,H) layout scattered 4B stores -> 436 MB WRITE_SIZE vs 38 logical).
__global__ __launch_bounds__(256) void k2_t(
    const float* __restrict__ x,
    const float* __restrict__ wb_r, const float* __restrict__ wb_i,
    float* __restrict__ t_r, float* __restrict__ t_i)
{
    __shared__ float xs[64*33];
    __shared__ float wbs[32*96];
    int bh = blockIdx.x;                  // b*192 + h
    int b = bh / 192, h = bh % 192;
    int tid = threadIdx.x;
    int c = tid >> 2, mg = tid & 3;
    float accr[12], acci[12];
    #pragma unroll
    for (int k = 0; k < 12; ++k) { accr[k] = 0.f; acci[k] = 0.f; }
    for (int w0 = 0; w0 < 192; w0 += 32) {
        for (int idx = tid; idx < 2048; idx += 256) {
            int cc = idx >> 5, ww = idx & 31;
            xs[cc*33 + ww] = x[((b*64 + cc)*192 + h)*192 + (w0 + ww)];
        }
        for (int idx = tid; idx < 1536; idx += 256) {
            int ww = idx / 48, mm = idx % 48;
            int g = (bh*192 + (w0 + ww))*48 + mm;
            wbs[ww*96 + mm]      = wb_r[g];
            wbs[ww*96 + 48 + mm] = wb_i[g];
        }
        __syncthreads();
        for (int ww = 0; ww < 32; ++ww) {
            float xv = xs[c*33 + ww];
            const float4* wr4 = (const float4*)(wbs + ww*96 + mg*12);
            const float4* wi4 = (const float4*)(wbs + ww*96 + 48 + mg*12);
            #pragma unroll
            for (int q = 0; q < 3; ++q) {
                float4 wr = wr4[q], wi = wi4[q];
                accr[4*q+0] = fmaf(xv, wr.x, accr[4*q+0]);
                accr[4*q+1] = fmaf(xv, wr.y, accr[4*q+1]);
                accr[4*q+2] = fmaf(xv, wr.z, accr[4*q+2]);
                accr[4*q+3] = fmaf(xv, wr.w, accr[4*q+3]);
                acci[4*q+0] = fmaf(xv, wi.x, acci[4*q+0]);
                acci[4*q+1] = fmaf(xv, wi.y, acci[4*q+1]);
                acci[4*q+2] = fmaf(xv, wi.z, acci[4*q+2]);
                acci[4*q+3] = fmaf(xv, wi.w, acci[4*q+3]);
            }
        }
        __syncthreads();
    }
    float* dr = t_r + ((bh)*64 + c)*48 + mg*12;
    float* di = t_i + ((bh)*64 + c)*48 + mg*12;
    #pragma unroll
    for (int q = 0; q < 3; ++q) {
        ((float4*)dr)[q] = make_float4(accr[4*q], accr[4*q+1], accr[4*q+2], accr[4*q+3]);
        ((float4*)di)[q] = make_float4(acci[4*q], acci[4*q+1], acci[4*q+2], acci[4*q+3]);
    }
}

// K4: t2[b,c,n,m] = sum_h t[b,c,h,m]*hb[b,m,h,n].  grid 384 = b*48+m.
// Reads t from (B,H,C,M2) (scattered, cheap); writes staging (B,M2,C,N)
// coalesced; k4b transposes to the (B,C,N,M) layout k5 streams.
__global__ __launch_bounds__(256) void k4_t2(
    const float* __restrict__ t_r, const float* __restrict__ t_i,
    const float* __restrict__ hb_r, const float* __restrict__ hb_i,
    float* __restrict__ t2t_r, float* __restrict__ t2t_i)
{
    __shared__ float tsr[64*33], tsi[64*33];
    __shared__ float hbs[32*96];
    int bm = blockIdx.x;                  // b*48 + m
    int b = bm / 48, m = bm % 48;
    int tid = threadIdx.x;
    int c = tid >> 2, ng = tid & 3;
    float ar[12], ai[12];
    #pragma unroll
    for (int k = 0; k < 12; ++k) { ar[k] = 0.f; ai[k] = 0.f; }
    for (int h0 = 0; h0 < 192; h0 += 32) {
        for (int idx = tid; idx < 2048; idx += 256) {
            int cc = idx >> 5, hh = idx & 31;
            int g = ((b*192 + h0 + hh)*64 + cc)*48 + m;
            tsr[cc*33 + hh] = t_r[g];
            tsi[cc*33 + hh] = t_i[g];
        }
        for (int idx = tid; idx < 1536; idx += 256) {
            int hh = idx / 48, nn = idx % 48;
            int g = (bm*192 + (h0 + hh))*48 + nn;
            hbs[hh*96 + nn]      = hb_r[g];
            hbs[hh*96 + 48 + nn] = hb_i[g];
        }
        __syncthreads();
        for (int hh = 0; hh < 32; ++hh) {
            float tr = tsr[c*33 + hh];
            float ti = tsi[c*33 + hh];
            const float4* hr4 = (const float4*)(hbs + hh*96 + ng*12);
            const float4* hi4 = (const float4*)(hbs + hh*96 + 48 + ng*12);
            #pragma unroll
            for (int q = 0; q < 3; ++q) {
                float4 hr = hr4[q], hi = hi4[q];
                ar[4*q+0] = fmaf(tr, hr.x, fmaf(-ti, hi.x, ar[4*q+0]));
                ai[4*q+0] = fmaf(tr, hi.x, fmaf( ti, hr.x, ai[4*q+0]));
                ar[4*q+1] = fmaf(tr, hr.y, fmaf(-ti, hi.y, ar[4*q+1]));
                ai[4*q+1] = fmaf(tr, hi.y, fmaf( ti, hr.y, ai[4*q+1]));
                ar[4*q+2] = fmaf(tr, hr.z, fmaf(-ti, hi.z, ar[4*q+2]));
                ai[4*q+2] = fmaf(tr, hi.z, fmaf( ti, hr.z, ai[4*q+2]));
                ar[4*q+3] = fmaf(tr, hr.w, fmaf(-ti, hi.w, ar[4*q+3]));
                ai[4*q+3] = fmaf(tr, hi.w, fmaf( ti, hr.w, ai[4*q+3]));
            }
        }
        __syncthreads();
    }
    float* dr = t2t_r + (bm*64 + c)*48 + ng*12;
    float* di = t2t_i + (bm*64 + c)*48 + ng*12;
    #pragma unroll
    for (int q = 0; q < 3; ++q) {
        ((float4*)dr)[q] = make_float4(ar[4*q], ar[4*q+1], ar[4*q+2], ar[4*q+3]);
        ((float4*)di)[q] = make_float4(ai[4*q], ai[4*q+1], ai[4*q+2], ai[4*q+3]);
    }
}

// K4b: transpose t2 staging (B,M2,C,N) -> (B,C,N,M2).  grid 512 = b*64+c.
__global__ __launch_bounds__(256) void k4b_tr(
    const float* __restrict__ sR, const float* __restrict__ sI,
    float* __restrict__ dR, float* __restrict__ dI)
{
    __shared__ float lr[48*49], li_[48*49];
    int bc = blockIdx.x;
    int b = bc >> 6, c = bc & 63;
    int tid = threadIdx.x;
    for (int idx = tid; idx < 2304; idx += 256) {
        int m = idx / 48, n = idx % 48;
        int g = ((b*48 + m)*64 + c)*48 + n;
        lr[m*49 + n]  = sR[g];
        li_[m*49 + n] = sI[g];
    }
    __syncthreads();
    for (int idx = tid; idx < 2304; idx += 256) {
        int n = idx / 48, m = idx % 48;
        int g = ((b*64 + c)*48 + n)*48 + m;
        dR[g] = lr[m*49 + n];
        dI[g] = li_[m*49 + n];
    }
}

// K5: proc[b,o,nm] = sum_i t2[b,i,nm]*Wf[o,i,nm].  grid 288 = 32 og x 9 chunks.
__global__ __launch_bounds__(256) void k5_proc(
    const float* __restrict__ t2_r, const float* __restrict__ t2_i,
    const float* __restrict__ fr, const float* __restrict__ fi,
    float* __restrict__ proc_r, float* __restrict__ proc_i)
{
    int og = blockIdx.x & 31;
    int ch = blockIdx.x >> 5;
    int nm = ch*256 + threadIdx.x;
    int o0 = og*2;
    float p0r[8], p0i[8], p1r[8], p1i[8];
    #pragma unroll
    for (int bb = 0; bb < 8; ++bb) { p0r[bb]=0.f; p0i[bb]=0.f; p1r[bb]=0.f; p1i[bb]=0.f; }
    for (int i = 0; i < 64; ++i) {
        float w0r = fr[(o0*64 + i)*2304 + nm];
        float w0i = fi[(o0*64 + i)*2304 + nm];
        float w1r = fr[((o0+1)*64 + i)*2304 + nm];
        float w1i = fi[((o0+1)*64 + i)*2304 + nm];
        #pragma unroll
        for (int bb = 0; bb < 8; ++bb) {
            float tr = t2_r[(bb*64 + i)*2304 + nm];
            float ti = t2_i[(bb*64 + i)*2304 + nm];
            p0r[bb] = fmaf(tr, w0r, fmaf(-ti, w0i, p0r[bb]));
            p0i[bb] = fmaf(tr, w0i, fmaf( ti, w0r, p0i[bb]));
            p1r[bb] = fmaf(tr, w1r, fmaf(-ti, w1i, p1r[bb]));
            p1i[bb] = fmaf(tr, w1i, fmaf( ti, w1r, p1i[bb]));
        }
    }
    #pragma unroll
    for (int bb = 0; bb < 8; ++bb) {
        proc_r[(bb*64 + o0)*2304 + nm]     = p0r[bb];
        proc_i[(bb*64 + o0)*2304 + nm]     = p0i[bb];
        proc_r[(bb*64 + o0 + 1)*2304 + nm] = p1r[bb];
        proc_i[(bb*64 + o0 + 1)*2304 + nm] = p1i[bb];
    }
}

// K6: rec_h[b,o,h,m] = sum_n proc[b,o,n,m]*conj(hb)[b,m,h,n].
// grid 1536 = (b*48+m)*4 + hq.  rec_h stored (B,M2,H,O).
__global__ __launch_bounds__(256) void k6_rech(
    const float* __restrict__ proc_r, const float* __restrict__ proc_i,
    const float* __restrict__ hb_r, const float* __restrict__ hb_i,
    float* __restrict__ rh_r, float* __restrict__ rh_i)
{
    __shared__ float psr[64*49], psi[64*49];
    __shared__ float hsr[48*52], hsi[48*52];
    int hq = blockIdx.x & 3;
    int bm = blockIdx.x >> 2;             // b*48 + m
    int b = bm / 48, m = bm % 48;
    int tid = threadIdx.x;
    int o = tid & 63, hg = tid >> 6;
    for (int idx = tid; idx < 3072; idx += 256) {
        int oo = idx / 48, nn = idx % 48;
        int g = (b*64 + oo)*2304 + nn*48 + m;
        psr[oo*49 + nn] = proc_r[g];
        psi[oo*49 + nn] = proc_i[g];
    }
    for (int idx = tid; idx < 2304; idx += 256) {
        int hh = idx / 48, nn = idx % 48;
        int g = (bm*192 + hq*48 + hh)*48 + nn;
        hsr[hh*52 + nn] = hb_r[g];
        hsi[hh*52 + nn] = hb_i[g];
    }
    __syncthreads();
    float accr[12], acci[12];
    #pragma unroll
    for (int j = 0; j < 12; ++j) { accr[j]=0.f; acci[j]=0.f; }
    for (int n4 = 0; n4 < 48; n4 += 4) {
        float prv[4], piv[4];
        #pragma unroll
        for (int q = 0; q < 4; ++q) {
            prv[q] = psr[o*49 + n4 + q];
            piv[q] = psi[o*49 + n4 + q];
        }
        #pragma unroll
        for (int j = 0; j < 12; ++j) {
            const float4 hr = *(const float4*)(hsr + (hg*12 + j)*52 + n4);
            const float4 hi = *(const float4*)(hsi + (hg*12 + j)*52 + n4);
            accr[j] += prv[0]*hr.x + piv[0]*hi.x
                     + prv[1]*hr.y + piv[1]*hi.y
                     + prv[2]*hr.z + piv[2]*hi.z
                     + prv[3]*hr.w + piv[3]*hi.w;
            acci[j] += piv[0]*hr.x - prv[0]*hi.x
                     + piv[1]*hr.y - prv[1]*hi.y
                     + piv[2]*hr.z - prv[2]*hi.z
                     + piv[3]*hr.w - prv[3]*hi.w;
        }
    }
    #pragma unroll
    for (int j = 0; j < 12; ++j) {
        int h = hq*48 + hg*12 + j;
        int a = (bm*192 + h)*64 + o;
        rh_r[a] = accr[j];
        rh_i[a] = acci[j];
    }
}

// K7: y[b,o,h,w] = (1/(H*W)) * sum_m rec_h[b,o,h,m]*conj(wb)[b,h,w,m] (real).
// grid 4608 = (b*192+h)*3 + wq.
__global__ __launch_bounds__(256) void k7_rec(
    const float* __restrict__ rh_r, const float* __restrict__ rh_i,
    const float* __restrict__ wb_r, const float* __restrict__ wb_i,
    float* __restrict__ y)
{
    __shared__ float asr[48*64], asi[48*64];
    __shared__ float wsr[64*49], wsi[64*49];
    int wq = blockIdx.x % 3;
    int bh = blockIdx.x / 3;              // b*192 + h
    int b = bh / 192, h = bh % 192;
    int tid = threadIdx.x;
    int w_l = tid & 63, og = tid >> 6;
    for (int idx = tid; idx < 3072; idx += 256) {
        int mm = idx >> 6, oo = idx & 63;
        int g = ((b*48 + mm)*192 + h)*64 + oo;
        asr[idx] = rh_r[g];
        asi[idx] = rh_i[g];
    }
    for (int idx = tid; idx < 3072; idx += 256) {
        int ww = idx / 48, mm = idx % 48;
        int g = (bh*192 + wq*64 + ww)*48 + mm;
        wsr[ww*49 + mm] = wb_r[g];
        wsi[ww*49 + mm] = wb_i[g];
    }
    __syncthreads();
    float acc[16];
    #pragma unroll
    for (int k = 0; k < 16; ++k) acc[k] = 0.f;
    for (int m = 0; m < 48; ++m) {
        float wr = wsr[w_l*49 + m];
        float wi = wsi[w_l*49 + m];
        #pragma unroll
        for (int q = 0; q < 4; ++q) {
            const float4 arv = *(const float4*)(asr + m*64 + og*16 + q*4);
            const float4 aiv = *(const float4*)(asi + m*64 + og*16 + q*4);
            acc[4*q+0] = fmaf(arv.x, wr, fmaf(aiv.x, wi, acc[4*q+0]));
            acc[4*q+1] = fmaf(arv.y, wr, fmaf(aiv.y, wi, acc[4*q+1]));
            acc[4*q+2] = fmaf(arv.z, wr, fmaf(aiv.z, wi, acc[4*q+2]));
            acc[4*q+3] = fmaf(arv.w, wr, fmaf(aiv.w, wi, acc[4*q+3]));
        }
    }
    const float s = 1.0f / 36864.0f;
    #pragma unroll
    for (int k = 0; k < 16; ++k) {
        int o = og*16 + k;
        y[((b*64 + o)*192 + h)*192 + wq*64 + w_l] = acc[k] * s;
    }
}

// K8: mixer GEMM + channel-LN + GELU + shortcut GEMM + GELU.  grid 4608.
__global__ __launch_bounds__(256) void k8_final(
    const float* __restrict__ y, const float* __restrict__ x,
    const float* __restrict__ mw, const float* __restrict__ mb,
    const float* __restrict__ nrm_g, const float* __restrict__ nrm_b,
    const float* __restrict__ sw, const float* __restrict__ sb,
    float* __restrict__ out)
{
    __shared__ float ys[64*65], xs[64*65];
    __shared__ float mws[64*68], sws[64*68];
    __shared__ float red[512];
    int wq = blockIdx.x % 3;
    int bh = blockIdx.x / 3;
    int b = bh / 192, h = bh % 192;
    int tid = threadIdx.x;
    int w_l = tid & 63, og = tid >> 6;
    int w0 = wq * 64;
    for (int cc = og; cc < 64; cc += 4) {
        int g = ((b*64 + cc)*192 + h)*192 + w0 + w_l;
        ys[cc*65 + w_l] = y[g];
        xs[cc*65 + w_l] = x[g];
    }
    for (int idx = tid; idx < 4096; idx += 256) {
        int oo = idx >> 6, cc = idx & 63;
        mws[cc*68 + oo] = mw[idx];
        sws[cc*68 + oo] = sw[idx];
    }
    __syncthreads();
    float accy[16], accs[16];
    #pragma unroll
    for (int k = 0; k < 16; ++k) { accy[k]=0.f; accs[k]=0.f; }
    for (int cc = 0; cc < 64; ++cc) {
        float yv = ys[cc*65 + w_l];
        float xv = xs[cc*65 + w_l];
        #pragma unroll
        for (int q = 0; q < 4; ++q) {
            const float4 m4 = *(const float4*)(mws + cc*68 + og*16 + q*4);
            const float4 s4 = *(const float4*)(sws + cc*68 + og*16 + q*4);
            accy[4*q+0] = fmaf(yv, m4.x, accy[4*q+0]);
            accy[4*q+1] = fmaf(yv, m4.y, accy[4*q+1]);
            accy[4*q+2] = fmaf(yv, m4.z, accy[4*q+2]);
            accy[4*q+3] = fmaf(yv, m4.w, accy[4*q+3]);
            accs[4*q+0] = fmaf(xv, s4.x, accs[4*q+0]);
            accs[4*q+1] = fmaf(xv, s4.y, accs[4*q+1]);
            accs[4*q+2] = fmaf(xv, s4.z, accs[4*q+2]);
            accs[4*q+3] = fmaf(xv, s4.w, accs[4*q+3]);
        }
    }
    float s1 = 0.f, s2 = 0.f;
    #pragma unroll
    for (int k = 0; k < 16; ++k) {
        int o = og*16 + k;
        accy[k] += mb[o];
        s1 += accy[k];
        s2 = fmaf(accy[k], accy[k], s2);
    }
    red[og*64 + w_l]       = s1;
    red[256 + og*64 + w_l] = s2;
    __syncthreads();
    float mu = (red[w_l] + red[64+w_l] + red[128+w_l] + red[192+w_l]) * 0.015625f;
    float ms = (red[256+w_l] + red[320+w_l] + red[384+w_l] + red[448+w_l]) * 0.015625f;
    float rstd = rsqrtf(ms - mu*mu + LN_EPS);
    #pragma unroll
    for (int k = 0; k < 16; ++k) {
        int o = og*16 + k;
        float v = (accy[k] - mu) * rstd * nrm_g[o] + nrm_b[o];
        v = gelu_f(v);
        float sc = accs[k] + sb[o];
        out[((b*64 + o)*192 + h)*192 + w0 + w_l] = gelu_f(v + sc);
    }
}

extern "C" void kernel_launch(void* const* d_in, const int* in_sizes, int n_in,
                              void* d_out, int out_size, void* d_ws, size_t ws_size,
                              hipStream_t stream)
{
    (void)in_sizes; (void)n_in; (void)out_size; (void)ws_size;
    const float* x    = (const float*)d_in[0];
    const float* wW0  = (const float*)d_in[1];
    const float* wb0  = (const float*)d_in[2];
    const float* wg0  = (const float*)d_in[3];
    const float* wbe0 = (const float*)d_in[4];
    const float* wW1  = (const float*)d_in[5];
    const float* wb1  = (const float*)d_in[6];
    const float* wg1  = (const float*)d_in[7];
    const float* wbe1 = (const float*)d_in[8];
    const float* wW2  = (const float*)d_in[9];
    const float* wb2  = (const float*)d_in[10];
    const float* hW0  = (const float*)d_in[11];
    const float* hb0  = (const float*)d_in[12];
    const float* hg0  = (const float*)d_in[13];
    const float* hbe0 = (const float*)d_in[14];
    const float* hW1  = (const float*)d_in[15];
    const float* hb1  = (const float*)d_in[16];
    const float* hg1  = (const float*)d_in[17];
    const float* hbe1 = (const float*)d_in[18];
    const float* hW2  = (const float*)d_in[19];
    const float* hb2  = (const float*)d_in[20];
    const float* fr   = (const float*)d_in[21];
    const float* fi   = (const float*)d_in[22];
    const float* mw   = (const float*)d_in[23];
    const float* mb   = (const float*)d_in[24];
    const float* ngp  = (const float*)d_in[25];
    const float* nbp  = (const float*)d_in[26];
    const float* sw   = (const float*)d_in[27];
    const float* sb   = (const float*)d_in[28];
    float* out = (float*)d_out;

    // workspace layout (floats); total 68,419,584 floats = 273.7 MB
    float* ws   = (float*)d_ws;
    float* wbr  = ws;                  // 14,155,776  (B,H,W,M2)
    float* wbi  = ws + 14155776;
    float* t_r  = ws + 28311552;       //  4,718,592  (B,H,C,M2)
    float* t_i  = ws + 33030144;
    float* hbr  = ws + 37748736;       //  3,538,944  (B,M2,H,M1)
    float* hbi  = ws + 41287680;
    float* t2r  = ws + 44826624;       //  1,179,648  (B,C,M1,M2)
    float* t2i  = ws + 46006272;
    float* prr  = ws + 47185920;       //  1,179,648  (B,O,M1,M2); also t2 staging (B,M2,C,N) before k5
    float* pri  = ws + 48365568;
    float* rhr  = t_r;                 // reuse: t dead after k4b
    float* rhi  = t_i;                 // (B,M2,H,O)
    float* yb   = ws + 49545216;       // 18,874,368  (B,O,H,W)
    uint4* wsw  = (uint4*)yb;          // swizzled MLP weights (dead until k7)

    k0_swizzle<<<dim3(6), dim3(256), 0, stream>>>(wW0, wW1, wW2, hW0, hW1, hW2, wsw);
    k1_mlp_w<<<dim3(4608), dim3(256), 0, stream>>>(x, wW0, wb0, wg0, wbe0,
                                                   wb1, wg1, wbe1, wb2, wsw, wbr, wbi);
    k2_t<<<dim3(1536), dim3(256), 0, stream>>>(x, wbr, wbi, t_r, t_i);
    k3_mlp_h<<<dim3(1152), dim3(256), 0, stream>>>(t_r, hW0, hb0, hg0, hbe0,
                                                   hb1, hg1, hbe1, hb2, wsw + 3584, hbr, hbi);
    // k4 writes staging (B,M2,C,N) into prr/pri (dead until k5); k4b
    // transposes into t2r/t2i (B,C,N,M); k5 then overwrites prr/pri with proc.
    k4_t2<<<dim3(384), dim3(256), 0, stream>>>(t_r, t_i, hbr, hbi, prr, pri);
    k4b_tr<<<dim3(512), dim3(256), 0, stream>>>(prr, pri, t2r, t2i);
    k5_proc<<<dim3(288), dim3(256), 0, stream>>>(t2r, t2i, fr, fi, prr, pri);
    k6_rech<<<dim3(1536), dim3(256), 0, stream>>>(prr, pri, hbr, hbi, rhr, rhi);
    k7_rec<<<dim3(4608), dim3(256), 0, stream>>>(rhr, rhi, wbr, wbi, yb);
    k8_final<<<dim3(4608), dim3(256), 0, stream>>>(yb, x, mw, mb, ngp, nbp, sw, sb, out);
}

// Round 5
// 858.842 us; speedup vs baseline: 1.2537x; 1.0418x over previous
//
#include <hip/hip_runtime.h>
#include <math.h>

#define LN_EPS 1e-5f

typedef short bf16x8 __attribute__((ext_vector_type(8)));
typedef float f32x4  __attribute__((ext_vector_type(4)));

__device__ __forceinline__ float gelu_f(float v) {
    return 0.5f * v * (1.0f + erff(v * 0.70710678118654752f));
}
__device__ __forceinline__ unsigned short f2bf(float f) {
    unsigned u = __float_as_uint(f);
    return (unsigned short)((u + 0x7fffu + ((u >> 16) & 1u)) >> 16);
}
__device__ __forceinline__ float bf2f(unsigned short h) {
    return __uint_as_float(((unsigned)h) << 16);
}

// ===========================================================================
// K0: swizzle MLP weights into MFMA B-fragment order, split hi/lo bf16.
// B[k][n], n = lane&15, k = (lane>>4)*8 + j.  Per tile: 128 uint4 = [hi|lo].
// ===========================================================================
__global__ __launch_bounds__(256) void k0_swizzle(
    const float* __restrict__ wW0, const float* __restrict__ wW1, const float* __restrict__ wW2,
    const float* __restrict__ hW0, const float* __restrict__ hW1, const float* __restrict__ hW2,
    uint4* __restrict__ dst)
{
    int mat = blockIdx.x;
    const float* W; int N, ntiles, base;
    switch (mat) {
      case 0: W=wW0; N=64; ntiles=8;  base=0;    break;
      case 1: W=wW1; N=64; ntiles=8;  base=1024; break;
      case 2: W=wW2; N=96; ntiles=12; base=2048; break;
      case 3: W=hW0; N=64; ntiles=8;  base=3584; break;
      case 4: W=hW1; N=64; ntiles=8;  base=4608; break;
      default:W=hW2; N=96; ntiles=12; base=5632; break;
    }
    int lane = threadIdx.x & 63;
    for (int t = threadIdx.x >> 6; t < ntiles; t += 4) {
        int nt = t >> 1, ks = t & 1;
        int n  = nt*16 + (lane & 15);
        int k0 = ks*32 + (lane >> 4)*8;
        unsigned hi[8], lo[8];
        #pragma unroll
        for (int j = 0; j < 8; ++j) {
            float v = W[(k0 + j)*N + n];
            unsigned short h = f2bf(v);
            hi[j] = h;
            lo[j] = f2bf(v - bf2f(h));
        }
        uint4 ph, pl;
        ph.x = hi[0] | (hi[1]<<16); ph.y = hi[2] | (hi[3]<<16);
        ph.z = hi[4] | (hi[5]<<16); ph.w = hi[6] | (hi[7]<<16);
        pl.x = lo[0] | (lo[1]<<16); pl.y = lo[2] | (lo[3]<<16);
        pl.z = lo[4] | (lo[5]<<16); pl.w = lo[6] | (lo[7]<<16);
        dst[base + t*128 + lane]      = ph;
        dst[base + t*128 + 64 + lane] = pl;
    }
}

// K0b: swizzle mixer/shortcut weights (transposed: B[k=c][n=o] = W[o*64+c]).
// Launched AFTER k5 into the then-dead t2 region (k8 needs weights that
// survive k7's overwrite of the yb/wsw region).
__global__ __launch_bounds__(256) void k0b_swizzle(
    const float* __restrict__ mw, const float* __restrict__ sw,
    uint4* __restrict__ dst)
{
    int mat = blockIdx.x;
    const float* W = mat ? sw : mw;
    int base = mat ? 1024 : 0;
    int lane = threadIdx.x & 63;
    for (int t = threadIdx.x >> 6; t < 8; t += 4) {
        int nt = t >> 1, ks = t & 1;
        int n  = nt*16 + (lane & 15);
        int k0 = ks*32 + (lane >> 4)*8;
        unsigned hi[8], lo[8];
        #pragma unroll
        for (int j = 0; j < 8; ++j) {
            float v = W[n*64 + (k0 + j)];
            unsigned short h = f2bf(v);
            hi[j] = h;
            lo[j] = f2bf(v - bf2f(h));
        }
        uint4 ph, pl;
        ph.x = hi[0] | (hi[1]<<16); ph.y = hi[2] | (hi[3]<<16);
        ph.z = hi[4] | (hi[5]<<16); ph.w = hi[6] | (hi[7]<<16);
        pl.x = lo[0] | (lo[1]<<16); pl.y = lo[2] | (lo[3]<<16);
        pl.z = lo[4] | (lo[5]<<16); pl.w = lo[6] | (lo[7]<<16);
        dst[base + t*128 + lane]      = ph;
        dst[base + t*128 + 64 + lane] = pl;
    }
}

// ===========================================================================
// Split-precision MFMA GEMM helper (wave-private 16 rows in LDS).
// ===========================================================================
template<int NT>
__device__ __forceinline__ void gemm64(
    const unsigned short* aHi, const unsigned short* aLo,
    const uint4* __restrict__ wsw, int tbase, int row, int quad, int lane,
    f32x4* acc)
{
    union U { uint4 u; bf16x8 b; };
    bf16x8 aH[2], aL[2];
    #pragma unroll
    for (int ks = 0; ks < 2; ++ks) {
        aH[ks] = *(const bf16x8*)&aHi[row*72 + ks*32 + quad*8];
        aL[ks] = *(const bf16x8*)&aLo[row*72 + ks*32 + quad*8];
    }
    #pragma unroll
    for (int nt = 0; nt < NT; ++nt) {
        f32x4 a = {0.f, 0.f, 0.f, 0.f};
        #pragma unroll
        for (int ks = 0; ks < 2; ++ks) {
            int t = tbase + nt*2 + ks;
            U bh, bl;
            bh.u = wsw[t*128 + lane];
            bl.u = wsw[t*128 + 64 + lane];
            a = __builtin_amdgcn_mfma_f32_16x16x32_bf16(aH[ks], bh.b, a, 0, 0, 0);
            a = __builtin_amdgcn_mfma_f32_16x16x32_bf16(aH[ks], bl.b, a, 0, 0, 0);
            a = __builtin_amdgcn_mfma_f32_16x16x32_bf16(aL[ks], bh.b, a, 0, 0, 0);
        }
        acc[nt] = a;
    }
}

__device__ __forceinline__ void ln_gelu_pass(
    f32x4* acc, const float* __restrict__ bias, const float* __restrict__ wrow,
    float coordBase, float coordScale,
    const float* __restrict__ gg, const float* __restrict__ bb,
    unsigned short* aHi, unsigned short* aLo, int rbase, int quad, int li)
{
    float vals[4][4];
    float s1[4] = {0,0,0,0}, s2[4] = {0,0,0,0};
    #pragma unroll
    for (int nt = 0; nt < 4; ++nt) {
        int col = nt*16 + li;
        float bv = bias[col];
        float br = wrow[col];
        #pragma unroll
        for (int rg = 0; rg < 4; ++rg) {
            float coord = (coordBase + (float)(rbase + quad*4 + rg)) * coordScale;
            float v = acc[nt][rg] + fmaf(coord, br, bv);
            vals[nt][rg] = v;
            s1[rg] += v;
            s2[rg] = fmaf(v, v, s2[rg]);
        }
    }
    #pragma unroll
    for (int d = 1; d < 16; d <<= 1) {
        #pragma unroll
        for (int rg = 0; rg < 4; ++rg) {
            s1[rg] += __shfl_xor(s1[rg], d, 64);
            s2[rg] += __shfl_xor(s2[rg], d, 64);
        }
    }
    #pragma unroll
    for (int nt = 0; nt < 4; ++nt) {
        int col = nt*16 + li;
        float gv = gg[col], bev = bb[col];
        #pragma unroll
        for (int rg = 0; rg < 4; ++rg) {
            float mu   = s1[rg] * 0.015625f;
            float rstd = rsqrtf(s2[rg]*0.015625f - mu*mu + LN_EPS);
            float v = gelu_f(fmaf((vals[nt][rg] - mu)*rstd, gv, bev));
            int r = rbase + quad*4 + rg;
            unsigned short hv = f2bf(v);
            aHi[r*72 + col] = hv;
            aLo[r*72 + col] = f2bf(v - bf2f(hv));
        }
    }
}

__device__ __forceinline__ void mlp_body(
    unsigned short* aHi, unsigned short* aLo,
    const uint4* __restrict__ wsw,
    const float* __restrict__ w0row,
    const float* __restrict__ b0, const float* __restrict__ g0, const float* __restrict__ be0,
    const float* __restrict__ b1, const float* __restrict__ g1, const float* __restrict__ be1,
    const float* __restrict__ b2,
    float coordBase,
    float* __restrict__ outR, float* __restrict__ outI, int pixBase)
{
    int tid = threadIdx.x;
    int wv = __builtin_amdgcn_readfirstlane(tid >> 6);
    int lane = tid & 63, li = lane & 15, quad = lane >> 4;
    int rbase = wv*16;
    int row = rbase + li;
    f32x4 acc[6];

    gemm64<4>(aHi, aLo, wsw, 0, row, quad, lane, acc);
    ln_gelu_pass(acc, b0, w0row, coordBase, 1.0f/191.0f, g0, be0, aHi, aLo, rbase, quad, li);
    gemm64<4>(aHi, aLo, wsw, 8, row, quad, lane, acc);
    ln_gelu_pass(acc, b1, b1, 0.f, 0.f, g1, be1, aHi, aLo, rbase, quad, li);
    gemm64<6>(aHi, aLo, wsw, 16, row, quad, lane, acc);
    #pragma unroll
    for (int nt = 0; nt < 6; ++nt) {
        int j = nt*16 + li;
        float bv = b2[j];
        #pragma unroll
        for (int rg = 0; rg < 4; ++rg) {
            float v = acc[nt][rg] + bv;
            int pix = pixBase + rbase + quad*4 + rg;
            if (nt < 3) outR[pix*48 + j]        = v;
            else        outI[pix*48 + (j - 48)] = v;
        }
    }
}

// K1: W-basis MLP.  grid 4608 = (b*192+h)*3 + wq.
__global__ __launch_bounds__(256) void k1_mlp_w(
    const float* __restrict__ x, const float* __restrict__ W0full,
    const float* __restrict__ b0, const float* __restrict__ g0, const float* __restrict__ be0,
    const float* __restrict__ b1, const float* __restrict__ g1, const float* __restrict__ be1,
    const float* __restrict__ b2,
    const uint4* __restrict__ wsw,
    float* __restrict__ wb_r, float* __restrict__ wb_i)
{
    __shared__ unsigned short aHi[64*72];
    __shared__ unsigned short aLo[64*72];
    int tid = threadIdx.x;
    int wv = __builtin_amdgcn_readfirstlane(tid >> 6);
    int lane = tid & 63, li = lane & 15, quad = lane >> 4;
    int wq = blockIdx.x % 3;
    int bh = blockIdx.x / 3;
    int b = bh / 192, h = bh % 192;
    int w0 = wq * 64;
    int r = wv*16 + li;
    #pragma unroll
    for (int cc = 0; cc < 16; ++cc) {
        int c = cc*4 + quad;
        float v = x[((b*64 + c)*192 + h)*192 + (w0 + r)];
        unsigned short hv = f2bf(v);
        aHi[r*72 + c] = hv;
        aLo[r*72 + c] = f2bf(v - bf2f(hv));
    }
    mlp_body(aHi, aLo, wsw, W0full + 64*64, b0, g0, be0, b1, g1, be1, b2,
             (float)w0, wb_r, wb_i, bh*192 + w0);
}

// K3: H-basis MLP.  grid 1152 = (b*48+m)*3 + hq.  t layout (B,H,C,M2).
__global__ __launch_bounds__(256) void k3_mlp_h(
    const float* __restrict__ t_r, const float* __restrict__ W0full,
    const float* __restrict__ b0, const float* __restrict__ g0, const float* __restrict__ be0,
    const float* __restrict__ b1, const float* __restrict__ g1, const float* __restrict__ be1,
    const float* __restrict__ b2,
    const uint4* __restrict__ wsw,
    float* __restrict__ hb_r, float* __restrict__ hb_i)
{
    __shared__ unsigned short aHi[64*72];
    __shared__ unsigned short aLo[64*72];
    int tid = threadIdx.x;
    int wv = __builtin_amdgcn_readfirstlane(tid >> 6);
    int lane = tid & 63, li = lane & 15, quad = lane >> 4;
    int hq = blockIdx.x % 3;
    int bm = blockIdx.x / 3;
    int b = bm / 48, m = bm % 48;
    int h0 = hq * 64;
    int r = wv*16 + li;
    #pragma unroll
    for (int cc = 0; cc < 16; ++cc) {
        int c = cc*4 + quad;
        float v = t_r[((b*192 + h0 + r)*64 + c)*48 + m];
        unsigned short hv = f2bf(v);
        aHi[r*72 + c] = hv;
        aLo[r*72 + c] = f2bf(v - bf2f(hv));
    }
    mlp_body(aHi, aLo, wsw, W0full + 64*64, b0, g0, be0, b1, g1, be1, b2,
             (float)h0, hb_r, hb_i, bm*192 + h0);
}

// K2: t[b,c,h,m] = sum_w x[b,c,h,w]*wb[b,h,w,m].  grid 1536 = b*192+h.
// t stored (B,H,C,M2) -> fully coalesced stores.
__global__ __launch_bounds__(256) void k2_t(
    const float* __restrict__ x,
    const float* __restrict__ wb_r, const float* __restrict__ wb_i,
    float* __restrict__ t_r, float* __restrict__ t_i)
{
    __shared__ float xs[64*33];
    __shared__ float wbs[32*96];
    int bh = blockIdx.x;                  // b*192 + h
    int b = bh / 192, h = bh % 192;
    int tid = threadIdx.x;
    int c = tid >> 2, mg = tid & 3;
    float accr[12], acci[12];
    #pragma unroll
    for (int k = 0; k < 12; ++k) { accr[k] = 0.f; acci[k] = 0.f; }
    for (int w0 = 0; w0 < 192; w0 += 32) {
        for (int idx = tid; idx < 2048; idx += 256) {
            int cc = idx >> 5, ww = idx & 31;
            xs[cc*33 + ww] = x[((b*64 + cc)*192 + h)*192 + (w0 + ww)];
        }
        for (int idx = tid; idx < 1536; idx += 256) {
            int ww = idx / 48, mm = idx % 48;
            int g = (bh*192 + (w0 + ww))*48 + mm;
            wbs[ww*96 + mm]      = wb_r[g];
            wbs[ww*96 + 48 + mm] = wb_i[g];
        }
        __syncthreads();
        for (int ww = 0; ww < 32; ++ww) {
            float xv = xs[c*33 + ww];
            const float4* wr4 = (const float4*)(wbs + ww*96 + mg*12);
            const float4* wi4 = (const float4*)(wbs + ww*96 + 48 + mg*12);
            #pragma unroll
            for (int q = 0; q < 3; ++q) {
                float4 wr = wr4[q], wi = wi4[q];
                accr[4*q+0] = fmaf(xv, wr.x, accr[4*q+0]);
                accr[4*q+1] = fmaf(xv, wr.y, accr[4*q+1]);
                accr[4*q+2] = fmaf(xv, wr.z, accr[4*q+2]);
                accr[4*q+3] = fmaf(xv, wr.w, accr[4*q+3]);
                acci[4*q+0] = fmaf(xv, wi.x, acci[4*q+0]);
                acci[4*q+1] = fmaf(xv, wi.y, acci[4*q+1]);
                acci[4*q+2] = fmaf(xv, wi.z, acci[4*q+2]);
                acci[4*q+3] = fmaf(xv, wi.w, acci[4*q+3]);
            }
        }
        __syncthreads();
    }
    float* dr = t_r + ((bh)*64 + c)*48 + mg*12;
    float* di = t_i + ((bh)*64 + c)*48 + mg*12;
    #pragma unroll
    for (int q = 0; q < 3; ++q) {
        ((float4*)dr)[q] = make_float4(accr[4*q], accr[4*q+1], accr[4*q+2], accr[4*q+3]);
        ((float4*)di)[q] = make_float4(acci[4*q], acci[4*q+1], acci[4*q+2], acci[4*q+3]);
    }
}

// K4: t2 contraction.  grid 384 = b*48+m.  Writes staging (B,M2,C,N).
__global__ __launch_bounds__(256) void k4_t2(
    const float* __restrict__ t_r, const float* __restrict__ t_i,
    const float* __restrict__ hb_r, const float* __restrict__ hb_i,
    float* __restrict__ t2t_r, float* __restrict__ t2t_i)
{
    __shared__ float tsr[64*33], tsi[64*33];
    __shared__ float hbs[32*96];
    int bm = blockIdx.x;                  // b*48 + m
    int b = bm / 48, m = bm % 48;
    int tid = threadIdx.x;
    int c = tid >> 2, ng = tid & 3;
    float ar[12], ai[12];
    #pragma unroll
    for (int k = 0; k < 12; ++k) { ar[k] = 0.f; ai[k] = 0.f; }
    for (int h0 = 0; h0 < 192; h0 += 32) {
        for (int idx = tid; idx < 2048; idx += 256) {
            int cc = idx >> 5, hh = idx & 31;
            int g = ((b*192 + h0 + hh)*64 + cc)*48 + m;
            tsr[cc*33 + hh] = t_r[g];
            tsi[cc*33 + hh] = t_i[g];
        }
        for (int idx = tid; idx < 1536; idx += 256) {
            int hh = idx / 48, nn = idx % 48;
            int g = (bm*192 + (h0 + hh))*48 + nn;
            hbs[hh*96 + nn]      = hb_r[g];
            hbs[hh*96 + 48 + nn] = hb_i[g];
        }
        __syncthreads();
        for (int hh = 0; hh < 32; ++hh) {
            float tr = tsr[c*33 + hh];
            float ti = tsi[c*33 + hh];
            const float4* hr4 = (const float4*)(hbs + hh*96 + ng*12);
            const float4* hi4 = (const float4*)(hbs + hh*96 + 48 + ng*12);
            #pragma unroll
            for (int q = 0; q < 3; ++q) {
                float4 hr = hr4[q], hi = hi4[q];
                ar[4*q+0] = fmaf(tr, hr.x, fmaf(-ti, hi.x, ar[4*q+0]));
                ai[4*q+0] = fmaf(tr, hi.x, fmaf( ti, hr.x, ai[4*q+0]));
                ar[4*q+1] = fmaf(tr, hr.y, fmaf(-ti, hi.y, ar[4*q+1]));
                ai[4*q+1] = fmaf(tr, hi.y, fmaf( ti, hr.y, ai[4*q+1]));
                ar[4*q+2] = fmaf(tr, hr.z, fmaf(-ti, hi.z, ar[4*q+2]));
                ai[4*q+2] = fmaf(tr, hi.z, fmaf( ti, hr.z, ai[4*q+2]));
                ar[4*q+3] = fmaf(tr, hr.w, fmaf(-ti, hi.w, ar[4*q+3]));
                ai[4*q+3] = fmaf(tr, hi.w, fmaf( ti, hr.w, ai[4*q+3]));
            }
        }
        __syncthreads();
    }
    float* dr = t2t_r + (bm*64 + c)*48 + ng*12;
    float* di = t2t_i + (bm*64 + c)*48 + ng*12;
    #pragma unroll
    for (int q = 0; q < 3; ++q) {
        ((float4*)dr)[q] = make_float4(ar[4*q], ar[4*q+1], ar[4*q+2], ar[4*q+3]);
        ((float4*)di)[q] = make_float4(ai[4*q], ai[4*q+1], ai[4*q+2], ai[4*q+3]);
    }
}

// K4b: transpose t2 staging (B,M2,C,N) -> (B,C,N,M2).  grid 512 = b*64+c.
__global__ __launch_bounds__(256) void k4b_tr(
    const float* __restrict__ sR, const float* __restrict__ sI,
    float* __restrict__ dR, float* __restrict__ dI)
{
    __shared__ float lr[48*49], li_[48*49];
    int bc = blockIdx.x;
    int b = bc >> 6, c = bc & 63;
    int tid = threadIdx.x;
    for (int idx = tid; idx < 2304; idx += 256) {
        int m = idx / 48, n = idx % 48;
        int g = ((b*48 + m)*64 + c)*48 + n;
        lr[m*49 + n]  = sR[g];
        li_[m*49 + n] = sI[g];
    }
    __syncthreads();
    for (int idx = tid; idx < 2304; idx += 256) {
        int n = idx / 48, m = idx % 48;
        int g = ((b*64 + c)*48 + n)*48 + m;
        dR[g] = lr[m*49 + n];
        dI[g] = li_[m*49 + n];
    }
}

// K5: proc[b,o,nm] = sum_i t2[b,i,nm]*Wf[o,i,nm].  grid 288.
__global__ __launch_bounds__(256) void k5_proc(
    const float* __restrict__ t2_r, const float* __restrict__ t2_i,
    const float* __restrict__ fr, const float* __restrict__ fi,
    float* __restrict__ proc_r, float* __restrict__ proc_i)
{
    int og = blockIdx.x & 31;
    int ch = blockIdx.x >> 5;
    int nm = ch*256 + threadIdx.x;
    int o0 = og*2;
    float p0r[8], p0i[8], p1r[8], p1i[8];
    #pragma unroll
    for (int bb = 0; bb < 8; ++bb) { p0r[bb]=0.f; p0i[bb]=0.f; p1r[bb]=0.f; p1i[bb]=0.f; }
    for (int i = 0; i < 64; ++i) {
        float w0r = fr[(o0*64 + i)*2304 + nm];
        float w0i = fi[(o0*64 + i)*2304 + nm];
        float w1r = fr[((o0+1)*64 + i)*2304 + nm];
        float w1i = fi[((o0+1)*64 + i)*2304 + nm];
        #pragma unroll
        for (int bb = 0; bb < 8; ++bb) {
            float tr = t2_r[(bb*64 + i)*2304 + nm];
            float ti = t2_i[(bb*64 + i)*2304 + nm];
            p0r[bb] = fmaf(tr, w0r, fmaf(-ti, w0i, p0r[bb]));
            p0i[bb] = fmaf(tr, w0i, fmaf( ti, w0r, p0i[bb]));
            p1r[bb] = fmaf(tr, w1r, fmaf(-ti, w1i, p1r[bb]));
            p1i[bb] = fmaf(tr, w1i, fmaf( ti, w1r, p1i[bb]));
        }
    }
    #pragma unroll
    for (int bb = 0; bb < 8; ++bb) {
        proc_r[(bb*64 + o0)*2304 + nm]     = p0r[bb];
        proc_i[(bb*64 + o0)*2304 + nm]     = p0i[bb];
        proc_r[(bb*64 + o0 + 1)*2304 + nm] = p1r[bb];
        proc_i[(bb*64 + o0 + 1)*2304 + nm] = p1i[bb];
    }
}

// K6: rec_h[b,o,h,m] = sum_n proc[b,o,n,m]*conj(hb)[b,m,h,n].
// grid 1536 = (b*48+m)*4 + hq.  rec_h stored (B,M2,H,O).
__global__ __launch_bounds__(256) void k6_rech(
    const float* __restrict__ proc_r, const float* __restrict__ proc_i,
    const float* __restrict__ hb_r, const float* __restrict__ hb_i,
    float* __restrict__ rh_r, float* __restrict__ rh_i)
{
    __shared__ float psr[64*49], psi[64*49];
    __shared__ float hsr[48*52], hsi[48*52];
    int hq = blockIdx.x & 3;
    int bm = blockIdx.x >> 2;             // b*48 + m
    int b = bm / 48, m = bm % 48;
    int tid = threadIdx.x;
    int o = tid & 63, hg = tid >> 6;
    for (int idx = tid; idx < 3072; idx += 256) {
        int oo = idx / 48, nn = idx % 48;
        int g = (b*64 + oo)*2304 + nn*48 + m;
        psr[oo*49 + nn] = proc_r[g];
        psi[oo*49 + nn] = proc_i[g];
    }
    for (int idx = tid; idx < 2304; idx += 256) {
        int hh = idx / 48, nn = idx % 48;
        int g = (bm*192 + hq*48 + hh)*48 + nn;
        hsr[hh*52 + nn] = hb_r[g];
        hsi[hh*52 + nn] = hb_i[g];
    }
    __syncthreads();
    float accr[12], acci[12];
    #pragma unroll
    for (int j = 0; j < 12; ++j) { accr[j]=0.f; acci[j]=0.f; }
    for (int n4 = 0; n4 < 48; n4 += 4) {
        float prv[4], piv[4];
        #pragma unroll
        for (int q = 0; q < 4; ++q) {
            prv[q] = psr[o*49 + n4 + q];
            piv[q] = psi[o*49 + n4 + q];
        }
        #pragma unroll
        for (int j = 0; j < 12; ++j) {
            const float4 hr = *(const float4*)(hsr + (hg*12 + j)*52 + n4);
            const float4 hi = *(const float4*)(hsi + (hg*12 + j)*52 + n4);
            accr[j] += prv[0]*hr.x + piv[0]*hi.x
                     + prv[1]*hr.y + piv[1]*hi.y
                     + prv[2]*hr.z + piv[2]*hi.z
                     + prv[3]*hr.w + piv[3]*hi.w;
            acci[j] += piv[0]*hr.x - prv[0]*hi.x
                     + piv[1]*hr.y - prv[1]*hi.y
                     + piv[2]*hr.z - prv[2]*hi.z
                     + piv[3]*hr.w - prv[3]*hi.w;
        }
    }
    #pragma unroll
    for (int j = 0; j < 12; ++j) {
        int h = hq*48 + hg*12 + j;
        int a = (bm*192 + h)*64 + o;
        rh_r[a] = accr[j];
        rh_i[a] = acci[j];
    }
}

// ===========================================================================
// K7 (MFMA): y[pix][o] = (1/HW) * sum_{k=0..95} A[pix][k]*B[k][o],
// A = [wbr | wbi] (K-concat, exact K=96), B = [rhr ; rhi].
// grid 4608 = (b*192+h)*3 + wq; 4 waves x 16 pixel rows.
// ===========================================================================
__global__ __launch_bounds__(256) void k7_rec(
    const float* __restrict__ rh_r, const float* __restrict__ rh_i,
    const float* __restrict__ wb_r, const float* __restrict__ wb_i,
    float* __restrict__ y)
{
    __shared__ unsigned short aHi[64*104];   // 64 rows x K=96 (+8 pad)
    __shared__ unsigned short aLo[64*104];
    __shared__ uint4 bfrag[1536];            // 12 tiles x [hi:64|lo@+768]
    float* cbuf = (float*)bfrag;             // alias, used after barrier

    int wq = blockIdx.x % 3;
    int bh = blockIdx.x / 3;
    int b = bh / 192, h = bh % 192;
    int w0 = wq * 64;
    int tid = threadIdx.x;
    int wv = __builtin_amdgcn_readfirstlane(tid >> 6);
    int lane = tid & 63, li = lane & 15, quad = lane >> 4;
    int rbase = wv*16;
    int row = rbase + li;

    // A staging: wb tile (64 pix x 48 m, r then i) -> hi/lo bf16
    {
        int pix = bh*192 + w0 + row;
        const float4* pr = (const float4*)(wb_r + pix*48) + quad*3;
        const float4* pi = (const float4*)(wb_i + pix*48) + quad*3;
        #pragma unroll
        for (int q = 0; q < 3; ++q) {
            float4 vr = pr[q];
            float4 vi = pi[q];
            int k0 = quad*12 + q*4;
            float vs[8] = {vr.x, vr.y, vr.z, vr.w, vi.x, vi.y, vi.z, vi.w};
            #pragma unroll
            for (int e = 0; e < 4; ++e) {
                unsigned short h1 = f2bf(vs[e]);
                aHi[row*104 + k0 + e] = h1;
                aLo[row*104 + k0 + e] = f2bf(vs[e] - bf2f(h1));
                unsigned short h2 = f2bf(vs[4+e]);
                aHi[row*104 + 48 + k0 + e] = h2;
                aLo[row*104 + 48 + k0 + e] = f2bf(vs[4+e] - bf2f(h2));
            }
        }
    }
    // B-fragment build: 12 tiles (t = nt*3 + ks), each rh element read once
    for (int t = tid >> 6; t < 12; t += 4) {
        int ks = t % 3;
        int nt = t / 3;
        int o = nt*16 + li;
        unsigned hi8[8], lo8[8];
        #pragma unroll
        for (int j = 0; j < 8; ++j) {
            int kk = ks*32 + quad*8 + j;
            const float* src = (kk < 48) ? rh_r : rh_i;
            int m = (kk < 48) ? kk : kk - 48;
            float v = src[((b*48 + m)*192 + h)*64 + o];
            unsigned short hv = f2bf(v);
            hi8[j] = hv;
            lo8[j] = f2bf(v - bf2f(hv));
        }
        uint4 ph, pl;
        ph.x = hi8[0] | (hi8[1]<<16); ph.y = hi8[2] | (hi8[3]<<16);
        ph.z = hi8[4] | (hi8[5]<<16); ph.w = hi8[6] | (hi8[7]<<16);
        pl.x = lo8[0] | (lo8[1]<<16); pl.y = lo8[2] | (lo8[3]<<16);
        pl.z = lo8[4] | (lo8[5]<<16); pl.w = lo8[6] | (lo8[7]<<16);
        bfrag[t*64 + lane]       = ph;
        bfrag[768 + t*64 + lane] = pl;
    }
    __syncthreads();

    union U { uint4 u; bf16x8 b; };
    bf16x8 aH[3], aL[3];
    #pragma unroll
    for (int ks = 0; ks < 3; ++ks) {
        aH[ks] = *(const bf16x8*)&aHi[row*104 + ks*32 + quad*8];
        aL[ks] = *(const bf16x8*)&aLo[row*104 + ks*32 + quad*8];
    }
    f32x4 acc[4];
    #pragma unroll
    for (int nt = 0; nt < 4; ++nt) {
        f32x4 a = {0.f, 0.f, 0.f, 0.f};
        #pragma unroll
        for (int ks = 0; ks < 3; ++ks) {
            int t = nt*3 + ks;
            U bh_, bl_;
            bh_.u = bfrag[t*64 + lane];
            bl_.u = bfrag[768 + t*64 + lane];
            a = __builtin_amdgcn_mfma_f32_16x16x32_bf16(aH[ks], bh_.b, a, 0, 0, 0);
            a = __builtin_amdgcn_mfma_f32_16x16x32_bf16(aH[ks], bl_.b, a, 0, 0, 0);
            a = __builtin_amdgcn_mfma_f32_16x16x32_bf16(aL[ks], bh_.b, a, 0, 0, 0);
        }
        acc[nt] = a;
    }
    __syncthreads();                       // all bfrag reads done; cbuf aliases it
    const float s = 1.0f / 36864.0f;
    #pragma unroll
    for (int nt = 0; nt < 4; ++nt) {
        int o = nt*16 + li;
        #pragma unroll
        for (int rg = 0; rg < 4; ++rg) {
            int prow = rbase + quad*4 + rg;
            cbuf[prow*67 + o] = acc[nt][rg] * s;
        }
    }
    __syncthreads();
    #pragma unroll
    for (int it = 0; it < 16; ++it) {
        int o = it*4 + (tid >> 6);
        int pix = tid & 63;
        y[((b*64 + o)*192 + h)*192 + w0 + pix] = cbuf[pix*67 + o];
    }
}

// ===========================================================================
// K8 (MFMA): mixer GEMM + channel-LN + GELU + shortcut GEMM + GELU.
// grid 4608; 4 waves x 16 pixel rows; weights pre-swizzled by k0b.
// x/y slabs staged sequentially through one hi/lo LDS buffer (wave-private).
// ===========================================================================
__global__ __launch_bounds__(256) void k8_final(
    const float* __restrict__ y, const float* __restrict__ x,
    const uint4* __restrict__ msw,
    const float* __restrict__ mb,
    const float* __restrict__ nrm_g, const float* __restrict__ nrm_b,
    const float* __restrict__ sb,
    float* __restrict__ out)
{
    __shared__ unsigned short smem[2*64*72];   // 18,432 B
    unsigned short* aHi = smem;
    unsigned short* aLo = smem + 64*72;
    float* cbuf = (float*)smem;                // 64*67*4 = 17,152 B alias

    int wq = blockIdx.x % 3;
    int bh = blockIdx.x / 3;
    int b = bh / 192, h = bh % 192;
    int w0 = wq * 64;
    int tid = threadIdx.x;
    int wv = __builtin_amdgcn_readfirstlane(tid >> 6);
    int lane = tid & 63, li = lane & 15, quad = lane >> 4;
    int rbase = wv*16;
    int row = rbase + li;

    // shortcut GEMM from x
    #pragma unroll
    for (int cc = 0; cc < 16; ++cc) {
        int c = cc*4 + quad;
        float v = x[((b*64 + c)*192 + h)*192 + w0 + row];
        unsigned short hv = f2bf(v);
        aHi[row*72 + c] = hv;
        aLo[row*72 + c] = f2bf(v - bf2f(hv));
    }
    f32x4 accs[4];
    gemm64<4>(aHi, aLo, msw, 8, row, quad, lane, accs);

    // mixer GEMM from y (overwrite wave-private rows; no barrier needed)
    #pragma unroll
    for (int cc = 0; cc < 16; ++cc) {
        int c = cc*4 + quad;
        float v = y[((b*64 + c)*192 + h)*192 + w0 + row];
        unsigned short hv = f2bf(v);
        aHi[row*72 + c] = hv;
        aLo[row*72 + c] = f2bf(v - bf2f(hv));
    }
    f32x4 accy[4];
    gemm64<4>(aHi, aLo, msw, 0, row, quad, lane, accy);

    // epilogue: +mb, LN over o (16-lane butterfly), gelu, +shortcut, gelu
    float vals[4][4];
    float s1[4] = {0,0,0,0}, s2[4] = {0,0,0,0};
    #pragma unroll
    for (int nt = 0; nt < 4; ++nt) {
        int o = nt*16 + li;
        float bv = mb[o];
        #pragma unroll
        for (int rg = 0; rg < 4; ++rg) {
            float v = accy[nt][rg] + bv;
            vals[nt][rg] = v;
            s1[rg] += v;
            s2[rg] = fmaf(v, v, s2[rg]);
        }
    }
    #pragma unroll
    for (int d = 1; d < 16; d <<= 1) {
        #pragma unroll
        for (int rg = 0; rg < 4; ++rg) {
            s1[rg] += __shfl_xor(s1[rg], d, 64);
            s2[rg] += __shfl_xor(s2[rg], d, 64);
        }
    }
    __syncthreads();                       // all LDS A-reads done; cbuf aliases
    #pragma unroll
    for (int nt = 0; nt < 4; ++nt) {
        int o = nt*16 + li;
        float gv = nrm_g[o], bev = nrm_b[o], sbv = sb[o];
        #pragma unroll
        for (int rg = 0; rg < 4; ++rg) {
            float mu   = s1[rg] * 0.015625f;
            float rstd = rsqrtf(s2[rg]*0.015625f - mu*mu + LN_EPS);
            float v  = gelu_f(fmaf((vals[nt][rg] - mu)*rstd, gv, bev));
            float sc = accs[nt][rg] + sbv;
            int prow = rbase + quad*4 + rg;
            cbuf[prow*67 + o] = gelu_f(v + sc);
        }
    }
    __syncthreads();
    #pragma unroll
    for (int it = 0; it < 16; ++it) {
        int o = it*4 + (tid >> 6);
        int pix = tid & 63;
        out[((b*64 + o)*192 + h)*192 + w0 + pix] = cbuf[pix*67 + o];
    }
}

extern "C" void kernel_launch(void* const* d_in, const int* in_sizes, int n_in,
                              void* d_out, int out_size, void* d_ws, size_t ws_size,
                              hipStream_t stream)
{
    (void)in_sizes; (void)n_in; (void)out_size; (void)ws_size;
    const float* x    = (const float*)d_in[0];
    const float* wW0  = (const float*)d_in[1];
    const float* wb0  = (const float*)d_in[2];
    const float* wg0  = (const float*)d_in[3];
    const float* wbe0 = (const float*)d_in[4];
    const float* wW1  = (const float*)d_in[5];
    const float* wb1  = (const float*)d_in[6];
    const float* wg1  = (const float*)d_in[7];
    const float* wbe1 = (const float*)d_in[8];
    const float* wW2  = (const float*)d_in[9];
    const float* wb2  = (const float*)d_in[10];
    const float* hW0  = (const float*)d_in[11];
    const float* hb0  = (const float*)d_in[12];
    const float* hg0  = (const float*)d_in[13];
    const float* hbe0 = (const float*)d_in[14];
    const float* hW1  = (const float*)d_in[15];
    const float* hb1  = (const float*)d_in[16];
    const float* hg1  = (const float*)d_in[17];
    const float* hbe1 = (const float*)d_in[18];
    const float* hW2  = (const float*)d_in[19];
    const float* hb2  = (const float*)d_in[20];
    const float* fr   = (const float*)d_in[21];
    const float* fi   = (const float*)d_in[22];
    const float* mw   = (const float*)d_in[23];
    const float* mb   = (const float*)d_in[24];
    const float* ngp  = (const float*)d_in[25];
    const float* nbp  = (const float*)d_in[26];
    const float* sw   = (const float*)d_in[27];
    const float* sb   = (const float*)d_in[28];
    float* out = (float*)d_out;

    float* ws   = (float*)d_ws;
    float* wbr  = ws;                  // 14,155,776  (B,H,W,M2)
    float* wbi  = ws + 14155776;
    float* t_r  = ws + 28311552;       //  4,718,592  (B,H,C,M2)
    float* t_i  = ws + 33030144;
    float* hbr  = ws + 37748736;       //  3,538,944  (B,M2,H,M1)
    float* hbi  = ws + 41287680;
    float* t2r  = ws + 44826624;       //  1,179,648  (B,C,M1,M2); after k5: msw
    float* t2i  = ws + 46006272;
    float* prr  = ws + 47185920;       //  staging (B,M2,C,N) then proc (B,O,M1,M2)
    float* pri  = ws + 48365568;
    float* rhr  = t_r;                 // reuse: t dead after k4b -> rec_h (B,M2,H,O)
    float* rhi  = t_i;
    float* yb   = ws + 49545216;       // 18,874,368  (B,O,H,W)
    uint4* wsw  = (uint4*)yb;          // MLP weights (dead until k7 writes y)
    uint4* msw  = (uint4*)t2r;         // mixer/shortcut weights (t2 dead after k5)

    k0_swizzle<<<dim3(6), dim3(256), 0, stream>>>(wW0, wW1, wW2, hW0, hW1, hW2, wsw);
    k1_mlp_w<<<dim3(4608), dim3(256), 0, stream>>>(x, wW0, wb0, wg0, wbe0,
                                                   wb1, wg1, wbe1, wb2, wsw, wbr, wbi);
    k2_t<<<dim3(1536), dim3(256), 0, stream>>>(x, wbr, wbi, t_r, t_i);
    k3_mlp_h<<<dim3(1152), dim3(256), 0, stream>>>(t_r, hW0, hb0, hg0, hbe0,
                                                   hb1, hg1, hbe1, hb2, wsw + 3584, hbr, hbi);
    k4_t2<<<dim3(384), dim3(256), 0, stream>>>(t_r, t_i, hbr, hbi, prr, pri);
    k4b_tr<<<dim3(512), dim3(256), 0, stream>>>(prr, pri, t2r, t2i);
    k5_proc<<<dim3(288), dim3(256), 0, stream>>>(t2r, t2i, fr, fi, prr, pri);
    k0b_swizzle<<<dim3(2), dim3(256), 0, stream>>>(mw, sw, msw);   // t2 now dead
    k6_rech<<<dim3(1536), dim3(256), 0, stream>>>(prr, pri, hbr, hbi, rhr, rhi);
    k7_rec<<<dim3(4608), dim3(256), 0, stream>>>(rhr, rhi, wbr, wbi, yb);
    k8_final<<<dim3(4608), dim3(256), 0, stream>>>(yb, x, msw, mb, ngp, nbp, sb, out);
}